// Round 1
// baseline (2027.405 us; speedup 1.0000x reference)
//
#include <hip/hip_runtime.h>
#include <hip/hip_bf16.h>

#define NB 8
#define NSEQ 1024
#define DMODEL 512
#define DF 2048
#define NEXP 8
#define NHEAD 8
#define HDIM 64
#define T_TOK (NB * NSEQ)

using bf16 = __hip_bfloat16;

// 16 FMAs of the 4x4 micro-tile, k-major LDS tiles As_t[16][68], Bs[16][68]
#define GEMM_TILE_K16()                                                        \
  _Pragma("unroll") for (int kk = 0; kk < 16; ++kk) {                          \
    const float4 a4 = *(const float4*)(&As_t[kk][ty * 4]);                     \
    const float4 b4 = *(const float4*)(&Bs[kk][tx * 4]);                       \
    acc[0][0] = fmaf(a4.x, b4.x, acc[0][0]);                                   \
    acc[0][1] = fmaf(a4.x, b4.y, acc[0][1]);                                   \
    acc[0][2] = fmaf(a4.x, b4.z, acc[0][2]);                                   \
    acc[0][3] = fmaf(a4.x, b4.w, acc[0][3]);                                   \
    acc[1][0] = fmaf(a4.y, b4.x, acc[1][0]);                                   \
    acc[1][1] = fmaf(a4.y, b4.y, acc[1][1]);                                   \
    acc[1][2] = fmaf(a4.y, b4.z, acc[1][2]);                                   \
    acc[1][3] = fmaf(a4.y, b4.w, acc[1][3]);                                   \
    acc[2][0] = fmaf(a4.z, b4.x, acc[2][0]);                                   \
    acc[2][1] = fmaf(a4.z, b4.y, acc[2][1]);                                   \
    acc[2][2] = fmaf(a4.z, b4.z, acc[2][2]);                                   \
    acc[2][3] = fmaf(a4.z, b4.w, acc[2][3]);                                   \
    acc[3][0] = fmaf(a4.w, b4.x, acc[3][0]);                                   \
    acc[3][1] = fmaf(a4.w, b4.y, acc[3][1]);                                   \
    acc[3][2] = fmaf(a4.w, b4.z, acc[3][2]);                                   \
    acc[3][3] = fmaf(a4.w, b4.w, acc[3][3]);                                   \
  }

// ---------------- Stage A: ax[b] = adj[b] (1024x1024) @ x[b] (1024x512) -----
__global__ __launch_bounds__(256) void k_adjx(const float* __restrict__ adj,
                                              const float* __restrict__ x,
                                              float* __restrict__ outp) {
  const int b = blockIdx.z;
  const int m0 = blockIdx.x * 64, n0 = blockIdx.y * 64;
  const float* A = adj + (size_t)b * NSEQ * NSEQ;
  const float* B = x + (size_t)b * NSEQ * DMODEL;
  float* C = outp + (size_t)b * NSEQ * DMODEL;
  __shared__ float As_t[16][68];
  __shared__ float Bs[16][68];
  const int t = threadIdx.x;
  const int tx = t & 15, ty = t >> 4;
  const int ar = t >> 2, ak = (t & 3) * 4;  // A: row ar, k ak..+4
  const int bk = t >> 4, bn = (t & 15) * 4; // B: k bk, col bn..+4
  float acc[4][4] = {};
  for (int k0 = 0; k0 < NSEQ; k0 += 16) {
    const float4 av = *(const float4*)(A + (size_t)(m0 + ar) * NSEQ + k0 + ak);
    const float4 bv = *(const float4*)(B + (size_t)(k0 + bk) * DMODEL + n0 + bn);
    __syncthreads();
    As_t[ak + 0][ar] = av.x; As_t[ak + 1][ar] = av.y;
    As_t[ak + 2][ar] = av.z; As_t[ak + 3][ar] = av.w;
    *(float4*)&Bs[bk][bn] = bv;
    __syncthreads();
    GEMM_TILE_K16();
  }
#pragma unroll
  for (int i = 0; i < 4; ++i) {
    float4 v = {acc[i][0], acc[i][1], acc[i][2], acc[i][3]};
    *(float4*)(C + (size_t)(m0 + ty * 4 + i) * DMODEL + n0 + tx * 4) = v;
  }
}

// ---------- NT GEMM: C[M,Nout] = A[M,K] @ Bw[Nout,K]^T + epilogue ----------
// EP==0: + bias[c] + addv[c] + addm[r,c]  (graphconv: +gc_b +root_emb +x)
// EP==1: + bias[c]
template <int EP>
__global__ __launch_bounds__(256) void k_gemm_nt(
    const float* __restrict__ A, const float* __restrict__ Bw,
    const float* __restrict__ bias, const float* __restrict__ addv,
    const float* __restrict__ addm, float* __restrict__ C, int K, int Nout) {
  const int m0 = blockIdx.x * 64, n0 = blockIdx.y * 64;
  __shared__ float As_t[16][68];
  __shared__ float Bs[16][68];
  const int t = threadIdx.x;
  const int tx = t & 15, ty = t >> 4;
  const int ar = t >> 2, ak = (t & 3) * 4;
  const int br = t >> 2, bkl = (t & 3) * 4;
  float acc[4][4] = {};
  for (int k0 = 0; k0 < K; k0 += 16) {
    const float4 av = *(const float4*)(A + (size_t)(m0 + ar) * K + k0 + ak);
    const float4 bv = *(const float4*)(Bw + (size_t)(n0 + br) * K + k0 + bkl);
    __syncthreads();
    As_t[ak + 0][ar] = av.x; As_t[ak + 1][ar] = av.y;
    As_t[ak + 2][ar] = av.z; As_t[ak + 3][ar] = av.w;
    Bs[bkl + 0][br] = bv.x; Bs[bkl + 1][br] = bv.y;
    Bs[bkl + 2][br] = bv.z; Bs[bkl + 3][br] = bv.w;
    __syncthreads();
    GEMM_TILE_K16();
  }
#pragma unroll
  for (int i = 0; i < 4; ++i) {
    const int r = m0 + ty * 4 + i;
    const int c = n0 + tx * 4;
    float4 v = {acc[i][0], acc[i][1], acc[i][2], acc[i][3]};
    const float4 bb = *(const float4*)(bias + c);
    v.x += bb.x; v.y += bb.y; v.z += bb.z; v.w += bb.w;
    if (EP == 0) {
      const float4 rv = *(const float4*)(addv + c);
      const float4 xv = *(const float4*)(addm + (size_t)r * Nout + c);
      v.x += rv.x + xv.x; v.y += rv.y + xv.y;
      v.z += rv.z + xv.z; v.w += rv.w + xv.w;
    }
    *(float4*)(C + (size_t)r * Nout + c) = v;
  }
}

// ---------------- Flash attention: 64 q-rows per block ----------------------
__global__ __launch_bounds__(256) void k_attn(const float* __restrict__ qkv,
                                              float* __restrict__ oatt) {
  const int q0 = blockIdx.x * 64, h = blockIdx.y, b = blockIdx.z;
  const int t = threadIdx.x;
  __shared__ float Qs[64][68];
  __shared__ float Ks[32][68];
  __shared__ float Vs[32][68];
  __shared__ float Ps[64][36];
  __shared__ float mrow[64], lrow[64];
  {  // load Q tile (scaled by 1/sqrt(64))
    const int qr = t >> 2, dl = (t & 3) * 16;
    const float* src =
        qkv + (size_t)(b * NSEQ + q0 + qr) * (3 * DMODEL) + h * HDIM + dl;
#pragma unroll
    for (int qq = 0; qq < 4; ++qq) {
      float4 v = *(const float4*)(src + qq * 4);
      v.x *= 0.125f; v.y *= 0.125f; v.z *= 0.125f; v.w *= 0.125f;
      *(float4*)&Qs[qr][dl + qq * 4] = v;
    }
    if (t < 64) { mrow[t] = -1e30f; lrow[t] = 0.f; }
  }
  float oacc[16] = {};
  const int orow = t >> 2, oc0 = (t & 3) * 16;
  const int sr = t >> 2, jb = t & 3;      // S cols jb + 4*jj
  const int kr = t >> 3, kd = (t & 7) * 8;
  for (int k0 = 0; k0 < NSEQ; k0 += 32) {
    __syncthreads();  // prev PV done before K/V overwrite
    {
      const float* kp =
          qkv + (size_t)(b * NSEQ + k0 + kr) * (3 * DMODEL) + DMODEL + h * HDIM + kd;
      const float4 ka = *(const float4*)kp;
      const float4 kb2 = *(const float4*)(kp + 4);
      const float4 va = *(const float4*)(kp + DMODEL);
      const float4 vb = *(const float4*)(kp + DMODEL + 4);
      *(float4*)&Ks[kr][kd] = ka;
      *(float4*)&Ks[kr][kd + 4] = kb2;
      *(float4*)&Vs[kr][kd] = va;
      *(float4*)&Vs[kr][kd + 4] = vb;
    }
    __syncthreads();
    // S = Q K^T  (8 cols per thread, strided to dodge bank conflicts)
    float s[8];
#pragma unroll
    for (int j = 0; j < 8; ++j) s[j] = 0.f;
    const float4* Qs4 = (const float4*)&Qs[0][0];
    const float4* Ks4 = (const float4*)&Ks[0][0];
#pragma unroll 4
    for (int kk4 = 0; kk4 < 16; ++kk4) {
      const float4 qv = Qs4[sr * 17 + kk4];
#pragma unroll
      for (int jj = 0; jj < 8; ++jj) {
        const float4 kv = Ks4[(jb + 4 * jj) * 17 + kk4];
        s[jj] = fmaf(qv.x, kv.x, s[jj]);
        s[jj] = fmaf(qv.y, kv.y, s[jj]);
        s[jj] = fmaf(qv.z, kv.z, s[jj]);
        s[jj] = fmaf(qv.w, kv.w, s[jj]);
      }
    }
    // online softmax (all state intra-wave: rows partitioned by wave)
    float lmax = s[0];
#pragma unroll
    for (int j = 1; j < 8; ++j) lmax = fmaxf(lmax, s[j]);
    lmax = fmaxf(lmax, __shfl_xor(lmax, 1));
    lmax = fmaxf(lmax, __shfl_xor(lmax, 2));
    const float mold = mrow[sr];
    const float mnew = fmaxf(mold, lmax);
    float psum = 0.f;
#pragma unroll
    for (int jj = 0; jj < 8; ++jj) {
      const float p = __expf(s[jj] - mnew);
      Ps[sr][jb + 4 * jj] = p;
      psum += p;
    }
    psum += __shfl_xor(psum, 1);
    psum += __shfl_xor(psum, 2);
    const float alpha = __expf(mold - mnew);
    if ((t & 3) == 0) {
      mrow[sr] = mnew;
      lrow[sr] = lrow[sr] * alpha + psum;
    }
#pragma unroll
    for (int c = 0; c < 16; ++c) oacc[c] *= alpha;
    // PV (reads Ps/Vs; Ps is intra-wave, Vs synced above)
    const float4* Vs4 = (const float4*)&Vs[0][0];
#pragma unroll 4
    for (int j = 0; j < 32; ++j) {
      const float p = Ps[orow][j];
#pragma unroll
      for (int c4 = 0; c4 < 4; ++c4) {
        const float4 vv = Vs4[j * 17 + (oc0 >> 2) + c4];
        oacc[c4 * 4 + 0] = fmaf(p, vv.x, oacc[c4 * 4 + 0]);
        oacc[c4 * 4 + 1] = fmaf(p, vv.y, oacc[c4 * 4 + 1]);
        oacc[c4 * 4 + 2] = fmaf(p, vv.z, oacc[c4 * 4 + 2]);
        oacc[c4 * 4 + 3] = fmaf(p, vv.w, oacc[c4 * 4 + 3]);
      }
    }
  }
  const float invl = 1.0f / lrow[orow];
  float* dst = oatt + (size_t)(b * NSEQ + q0 + orow) * DMODEL + h * HDIM + oc0;
#pragma unroll
  for (int c4 = 0; c4 < 4; ++c4) {
    float4 v = {oacc[c4 * 4 + 0] * invl, oacc[c4 * 4 + 1] * invl,
                oacc[c4 * 4 + 2] * invl, oacc[c4 * 4 + 3] * invl};
    *(float4*)(dst + c4 * 4) = v;
  }
}

// ---------------- LayerNorm( a + b ) -> out --------------------------------
__global__ __launch_bounds__(256) void k_ln_add(
    const float* __restrict__ a, const float* __restrict__ bsrc,
    const float* __restrict__ g, const float* __restrict__ be,
    float* __restrict__ outp) {
  const int tok = blockIdx.x;
  const int t = threadIdx.x;
  float2 v;
  {
    const float2 va = *(const float2*)(a + (size_t)tok * DMODEL + t * 2);
    const float2 vb = *(const float2*)(bsrc + (size_t)tok * DMODEL + t * 2);
    v.x = va.x + vb.x; v.y = va.y + vb.y;
  }
  float s1 = v.x + v.y, s2 = v.x * v.x + v.y * v.y;
#pragma unroll
  for (int o = 32; o; o >>= 1) { s1 += __shfl_down(s1, o); s2 += __shfl_down(s2, o); }
  __shared__ float sm1[4], sm2[4];
  if ((t & 63) == 0) { sm1[t >> 6] = s1; sm2[t >> 6] = s2; }
  __syncthreads();
  s1 = sm1[0] + sm1[1] + sm1[2] + sm1[3];
  s2 = sm2[0] + sm2[1] + sm2[2] + sm2[3];
  const float mean = s1 * (1.f / DMODEL);
  const float var = s2 * (1.f / DMODEL) - mean * mean;
  const float rstd = rsqrtf(var + 1e-5f);
  float2 o;
  o.x = (v.x - mean) * rstd * g[t * 2] + be[t * 2];
  o.y = (v.y - mean) * rstd * g[t * 2 + 1] + be[t * 2 + 1];
  *(float2*)(outp + (size_t)tok * DMODEL + t * 2) = o;
}

// ---------------- MoE gating: top-2 + normalized weights -------------------
__global__ __launch_bounds__(256) void k_gate(const float* __restrict__ x2,
                                              const float* __restrict__ gw,
                                              int* __restrict__ eidx,
                                              float* __restrict__ ewgt,
                                              int* __restrict__ ecnt) {
  const int tok = blockIdx.x * 256 + threadIdx.x;
  float lg[NEXP] = {};
  const float* px = x2 + (size_t)tok * DMODEL;
  for (int i = 0; i < DMODEL; i += 4) {
    const float4 xv = *(const float4*)(px + i);
#pragma unroll
    for (int e = 0; e < NEXP; ++e) {
      const float4 wv = *(const float4*)(gw + e * DMODEL + i);
      lg[e] += xv.x * wv.x + xv.y * wv.y + xv.z * wv.z + xv.w * wv.w;
    }
  }
  int i0 = 0; float b0 = lg[0];
#pragma unroll
  for (int e = 1; e < NEXP; ++e) if (lg[e] > b0) { b0 = lg[e]; i0 = e; }
  int i1 = -1; float v1 = -1e30f;
#pragma unroll
  for (int e = 0; e < NEXP; ++e)
    if (e != i0 && lg[e] > v1) { v1 = lg[e]; i1 = e; }
  const float tt = __expf(v1 - b0);  // softmax over the 2 logits
  const float w0 = 1.f / (1.f + tt), w1 = tt / (1.f + tt);
  eidx[tok * 2] = i0; eidx[tok * 2 + 1] = i1;
  ewgt[tok * 2] = w0; ewgt[tok * 2 + 1] = w1;
  atomicAdd(&ecnt[i0], 1);
  atomicAdd(&ecnt[i1], 1);
}

__global__ void k_zero(int* __restrict__ p, int n) {
  const int i = blockIdx.x * blockDim.x + threadIdx.x;
  if (i < n) p[i] = 0;
}

__global__ void k_offsets(const int* __restrict__ ecnt, int* __restrict__ eoff) {
  if (threadIdx.x == 0) {
    int s = 0;
    for (int e = 0; e < NEXP; ++e) { eoff[e] = s; s += ecnt[e]; }
  }
}

__global__ __launch_bounds__(256) void k_scatter(
    const int* __restrict__ eidx, const int* __restrict__ eoff,
    int* __restrict__ efill, int* __restrict__ rtok, int* __restrict__ t2s) {
  const int tok = blockIdx.x * 256 + threadIdx.x;
#pragma unroll
  for (int k = 0; k < 2; ++k) {
    const int e = eidx[tok * 2 + k];
    const int pos = atomicAdd(&efill[e], 1);
    const int slot = eoff[e] + pos;
    rtok[slot] = tok;
    t2s[tok * 2 + k] = slot;
  }
}

// ------- MoE GEMM1: hid[slot] = gelu(x2[tok] @ W1[e] + b1[e]) (bf16) -------
__global__ __launch_bounds__(256) void k_moe1(
    const float* __restrict__ x2, const float* __restrict__ W1,
    const float* __restrict__ b1, const int* __restrict__ rtok,
    const int* __restrict__ ecnt, const int* __restrict__ eoff,
    bf16* __restrict__ hid) {
  const int e = blockIdx.z;
  const int cnt = ecnt[e];
  const int m0 = blockIdx.y * 64;
  if (m0 >= cnt) return;
  const int off = eoff[e];
  const int n0 = blockIdx.x * 64;
  const float* Bw = W1 + (size_t)e * DMODEL * DF;
  __shared__ float As_t[16][68];
  __shared__ float Bs[16][68];
  __shared__ int rowtok[64];
  const int t = threadIdx.x;
  if (t < 64) rowtok[t] = (m0 + t < cnt) ? rtok[off + m0 + t] : -1;
  __syncthreads();
  const int tx = t & 15, ty = t >> 4;
  const int ar = t >> 2, ak = (t & 3) * 4;
  const int bk = t >> 4, bn = (t & 15) * 4;
  const int tk = rowtok[ar];
  float acc[4][4] = {};
  for (int k0 = 0; k0 < DMODEL; k0 += 16) {
    const float4 av = (tk >= 0)
        ? *(const float4*)(x2 + (size_t)tk * DMODEL + k0 + ak)
        : make_float4(0.f, 0.f, 0.f, 0.f);
    const float4 bv = *(const float4*)(Bw + (size_t)(k0 + bk) * DF + n0 + bn);
    __syncthreads();
    As_t[ak + 0][ar] = av.x; As_t[ak + 1][ar] = av.y;
    As_t[ak + 2][ar] = av.z; As_t[ak + 3][ar] = av.w;
    *(float4*)&Bs[bk][bn] = bv;
    __syncthreads();
    GEMM_TILE_K16();
  }
#pragma unroll
  for (int i = 0; i < 4; ++i) {
    const int r = m0 + ty * 4 + i;
    if (r < cnt) {
#pragma unroll
      for (int j = 0; j < 4; ++j) {
        const int c = n0 + tx * 4 + j;
        float v = acc[i][j] + b1[e * DF + c];
        v = v * 0.5f * (1.f + erff(v * 0.70710678118f));  // exact gelu
        hid[(size_t)(off + r) * DF + c] = __float2bfloat16(v);
      }
    }
  }
}

// ------- MoE GEMM2: y[slot] = hid[slot] @ W2[e] + b2[e] (fp32 out) ---------
__global__ __launch_bounds__(256) void k_moe2(
    const bf16* __restrict__ hid, const float* __restrict__ W2,
    const float* __restrict__ b2, const int* __restrict__ ecnt,
    const int* __restrict__ eoff, float* __restrict__ ybuf) {
  const int e = blockIdx.z;
  const int cnt = ecnt[e];
  const int m0 = blockIdx.y * 64;
  if (m0 >= cnt) return;
  const int off = eoff[e];
  const int n0 = blockIdx.x * 64;
  const float* Bw = W2 + (size_t)e * DF * DMODEL;
  const unsigned short* hp = (const unsigned short*)hid;
  __shared__ float As_t[16][68];
  __shared__ float Bs[16][68];
  const int t = threadIdx.x;
  const int tx = t & 15, ty = t >> 4;
  const int ar = t >> 2, ak = (t & 3) * 4;
  const int bk = t >> 4, bn = (t & 15) * 4;
  float acc[4][4] = {};
  for (int k0 = 0; k0 < DF; k0 += 16) {
    const ushort4 hv = *(const ushort4*)(hp + (size_t)(off + m0 + ar) * DF + k0 + ak);
    const float4 bv = *(const float4*)(Bw + (size_t)(k0 + bk) * DMODEL + n0 + bn);
    __syncthreads();
    As_t[ak + 0][ar] = __uint_as_float((unsigned)hv.x << 16);
    As_t[ak + 1][ar] = __uint_as_float((unsigned)hv.y << 16);
    As_t[ak + 2][ar] = __uint_as_float((unsigned)hv.z << 16);
    As_t[ak + 3][ar] = __uint_as_float((unsigned)hv.w << 16);
    *(float4*)&Bs[bk][bn] = bv;
    __syncthreads();
    GEMM_TILE_K16();
  }
#pragma unroll
  for (int i = 0; i < 4; ++i) {
    const int r = m0 + ty * 4 + i;
    if (r < cnt) {
      const int c = n0 + tx * 4;
      float4 v = {acc[i][0], acc[i][1], acc[i][2], acc[i][3]};
      const float4 bb = *(const float4*)(b2 + e * DMODEL + c);
      v.x += bb.x; v.y += bb.y; v.z += bb.z; v.w += bb.w;
      *(float4*)(ybuf + (size_t)(off + r) * DMODEL + c) = v;
    }
  }
}

// -------- combine: out = LN( x2 + w0*y[s0] + w1*y[s1] ) --------------------
__global__ __launch_bounds__(256) void k_ln2(
    const float* __restrict__ x2, const float* __restrict__ ybuf,
    const int* __restrict__ t2s, const float* __restrict__ ewgt,
    const float* __restrict__ g, const float* __restrict__ be,
    float* __restrict__ outp) {
  const int tok = blockIdx.x;
  const int t = threadIdx.x;
  const int s0 = t2s[tok * 2], s1i = t2s[tok * 2 + 1];
  const float w0 = ewgt[tok * 2], w1 = ewgt[tok * 2 + 1];
  float2 v;
  {
    const float2 a = *(const float2*)(x2 + (size_t)tok * DMODEL + t * 2);
    const float2 y0 = *(const float2*)(ybuf + (size_t)s0 * DMODEL + t * 2);
    const float2 y1 = *(const float2*)(ybuf + (size_t)s1i * DMODEL + t * 2);
    v.x = a.x + w0 * y0.x + w1 * y1.x;
    v.y = a.y + w0 * y0.y + w1 * y1.y;
  }
  float sum1 = v.x + v.y, sum2 = v.x * v.x + v.y * v.y;
#pragma unroll
  for (int o = 32; o; o >>= 1) { sum1 += __shfl_down(sum1, o); sum2 += __shfl_down(sum2, o); }
  __shared__ float sm1[4], sm2[4];
  if ((t & 63) == 0) { sm1[t >> 6] = sum1; sm2[t >> 6] = sum2; }
  __syncthreads();
  sum1 = sm1[0] + sm1[1] + sm1[2] + sm1[3];
  sum2 = sm2[0] + sm2[1] + sm2[2] + sm2[3];
  const float mean = sum1 * (1.f / DMODEL);
  const float var = sum2 * (1.f / DMODEL) - mean * mean;
  const float rstd = rsqrtf(var + 1e-5f);
  float2 o;
  o.x = (v.x - mean) * rstd * g[t * 2] + be[t * 2];
  o.y = (v.y - mean) * rstd * g[t * 2 + 1] + be[t * 2 + 1];
  *(float2*)(outp + (size_t)tok * DMODEL + t * 2) = o;
}

extern "C" void kernel_launch(void* const* d_in, const int* in_sizes, int n_in,
                              void* d_out, int out_size, void* d_ws,
                              size_t ws_size, hipStream_t stream) {
  const float* x      = (const float*)d_in[0];
  const float* adj    = (const float*)d_in[1];
  const float* gc_w   = (const float*)d_in[2];
  const float* gc_b   = (const float*)d_in[3];
  const float* root   = (const float*)d_in[4];
  const float* in_w   = (const float*)d_in[5];
  const float* in_b   = (const float*)d_in[6];
  const float* out_w  = (const float*)d_in[7];
  const float* out_b  = (const float*)d_in[8];
  const float* ln1_g  = (const float*)d_in[9];
  const float* ln1_b  = (const float*)d_in[10];
  const float* ln2_g  = (const float*)d_in[11];
  const float* ln2_b  = (const float*)d_in[12];
  const float* gate_w = (const float*)d_in[13];
  const float* W1     = (const float*)d_in[14];
  const float* b1     = (const float*)d_in[15];
  const float* W2     = (const float*)d_in[16];
  const float* b2     = (const float*)d_in[17];
  float* outp = (float*)d_out;

  // ws layout (needs ~118 MB). Aliasing is lifetime-safe (see stage order).
  constexpr size_t TD4 = (size_t)T_TOK * DMODEL * 4;
  char* W = (char*)d_ws;
  float* ax    = (float*)(W + 0);        // stage A out; then oproj; then ybuf alias
  float* oatt  = (float*)(W + TD4);      // attn out; then ybuf alias
  float* x1    = (float*)(W + 2 * TD4);  // graphconv residual out; hid alias later
  float* qkv   = (float*)(W + 3 * TD4);  // 3*TD4 bytes; hid alias later
  float* x2    = (float*)(W + 6 * TD4);  // post-LN1
  char* misc   = W + 7 * TD4;
  int*   eidx  = (int*)misc;                       // 2T ints
  float* ewgt  = (float*)(misc + 65536);           // 2T floats
  int*   ecnt  = (int*)(misc + 131072);            // 8
  int*   eoff  = (int*)(misc + 131072 + 128);      // 8
  int*   efill = (int*)(misc + 131072 + 256);      // 8
  int*   rtok  = (int*)(misc + 131072 + 512);      // 2T ints
  int*   t2s   = (int*)(misc + 131072 + 512 + 65536);
  bf16*  hid   = (bf16*)(W + 2 * TD4);   // 64 MiB, aliases x1+qkv (dead by MoE)
  float* ybuf  = (float*)(W + 0);        // 32 MiB, aliases ax+oatt (dead by MoE)
  float* oproj = ax;

  // A: ax = adj @ x
  k_adjx<<<dim3(16, 8, 8), 256, 0, stream>>>(adj, x, ax);
  // B: x1 = x + ax @ gc_w^T + gc_b + root_emb
  k_gemm_nt<0><<<dim3(128, 8), 256, 0, stream>>>(ax, gc_w, gc_b, root, x, x1,
                                                 DMODEL, DMODEL);
  // C: qkv = x1 @ in_w^T + in_b
  k_gemm_nt<1><<<dim3(128, 24), 256, 0, stream>>>(x1, in_w, in_b, nullptr,
                                                  nullptr, qkv, DMODEL, 3 * DMODEL);
  // D: attention
  k_attn<<<dim3(16, 8, 8), 256, 0, stream>>>(qkv, oatt);
  // E: oproj = oatt @ out_w^T + out_b
  k_gemm_nt<1><<<dim3(128, 8), 256, 0, stream>>>(oatt, out_w, out_b, nullptr,
                                                 nullptr, oproj, DMODEL, DMODEL);
  // LN1: x2 = LN(x1 + oproj)
  k_ln_add<<<dim3(T_TOK), 256, 0, stream>>>(x1, oproj, ln1_g, ln1_b, x2);
  // MoE routing
  k_zero<<<dim3(1), 128, 0, stream>>>((int*)(misc + 131072), 128);
  k_gate<<<dim3(T_TOK / 256), 256, 0, stream>>>(x2, gate_w, eidx, ewgt, ecnt);
  k_offsets<<<dim3(1), 64, 0, stream>>>(ecnt, eoff);
  k_scatter<<<dim3(T_TOK / 256), 256, 0, stream>>>(eidx, eoff, efill, rtok, t2s);
  // MoE expert FFN (top-2 routed == reference dense result)
  k_moe1<<<dim3(DF / 64, 128, NEXP), 256, 0, stream>>>(x2, W1, b1, rtok, ecnt,
                                                       eoff, hid);
  k_moe2<<<dim3(DMODEL / 64, 128, NEXP), 256, 0, stream>>>(hid, W2, b2, ecnt,
                                                           eoff, ybuf);
  // combine + LN2 -> out
  k_ln2<<<dim3(T_TOK), 256, 0, stream>>>(x2, ybuf, t2s, ewgt, ln2_g, ln2_b,
                                         outp);
}

// Round 3
// 1282.931 us; speedup vs baseline: 1.5803x; 1.5803x over previous
//
#include <hip/hip_runtime.h>
#include <hip/hip_bf16.h>

#define NB 8
#define NSEQ 1024
#define DMODEL 512
#define DF 2048
#define NEXP 8
#define NHEAD 8
#define HDIM 64
#define T_TOK (NB * NSEQ)

typedef unsigned short u16;
typedef float f32x4_t __attribute__((ext_vector_type(4)));
typedef __bf16 bf16x8_t __attribute__((ext_vector_type(8)));

__device__ __forceinline__ u16 f2b(float f) {
  __hip_bfloat16 h = __float2bfloat16(f);
  return *reinterpret_cast<u16*>(&h);
}
__device__ __forceinline__ float b2f(u16 u) {
  return __uint_as_float((unsigned)u << 16);
}
// async global->LDS, 16B per lane; lds ptr must be wave-uniform
__device__ __forceinline__ void gl_lds16(const u16* g, u16* l) {
  __builtin_amdgcn_global_load_lds(
      (const __attribute__((address_space(1))) unsigned int*)g,
      (__attribute__((address_space(3))) unsigned int*)l, 16, 0, 0);
}

// 16 FMAs of the 4x4 micro-tile, k-major LDS tiles As_t[16][68], Bs[16][68]
#define GEMM_TILE_K16()                                                        \
  _Pragma("unroll") for (int kk = 0; kk < 16; ++kk) {                          \
    const float4 a4 = *(const float4*)(&As_t[kk][ty * 4]);                     \
    const float4 b4 = *(const float4*)(&Bs[kk][tx * 4]);                       \
    acc[0][0] = fmaf(a4.x, b4.x, acc[0][0]);                                   \
    acc[0][1] = fmaf(a4.x, b4.y, acc[0][1]);                                   \
    acc[0][2] = fmaf(a4.x, b4.z, acc[0][2]);                                   \
    acc[0][3] = fmaf(a4.x, b4.w, acc[0][3]);                                   \
    acc[1][0] = fmaf(a4.y, b4.x, acc[1][0]);                                   \
    acc[1][1] = fmaf(a4.y, b4.y, acc[1][1]);                                   \
    acc[1][2] = fmaf(a4.y, b4.z, acc[1][2]);                                   \
    acc[1][3] = fmaf(a4.y, b4.w, acc[1][3]);                                   \
    acc[2][0] = fmaf(a4.z, b4.x, acc[2][0]);                                   \
    acc[2][1] = fmaf(a4.z, b4.y, acc[2][1]);                                   \
    acc[2][2] = fmaf(a4.z, b4.z, acc[2][2]);                                   \
    acc[2][3] = fmaf(a4.z, b4.w, acc[2][3]);                                   \
    acc[3][0] = fmaf(a4.w, b4.x, acc[3][0]);                                   \
    acc[3][1] = fmaf(a4.w, b4.y, acc[3][1]);                                   \
    acc[3][2] = fmaf(a4.w, b4.z, acc[3][2]);                                   \
    acc[3][3] = fmaf(a4.w, b4.w, acc[3][3]);                                   \
  }

// ---------------- Stage A: ax[b] = adj[b] @ x[b] ---------------------------
__global__ __launch_bounds__(256) void k_adjx(const float* __restrict__ adj,
                                              const float* __restrict__ x,
                                              float* __restrict__ outp) {
  const int b = blockIdx.z;
  const int m0 = blockIdx.x * 64, n0 = blockIdx.y * 64;
  const float* A = adj + (size_t)b * NSEQ * NSEQ;
  const float* B = x + (size_t)b * NSEQ * DMODEL;
  float* C = outp + (size_t)b * NSEQ * DMODEL;
  __shared__ float As_t[16][68];
  __shared__ float Bs[16][68];
  const int t = threadIdx.x;
  const int tx = t & 15, ty = t >> 4;
  const int ar = t >> 2, ak = (t & 3) * 4;
  const int bk = t >> 4, bn = (t & 15) * 4;
  float acc[4][4] = {};
  for (int k0 = 0; k0 < NSEQ; k0 += 16) {
    const float4 av = *(const float4*)(A + (size_t)(m0 + ar) * NSEQ + k0 + ak);
    const float4 bv = *(const float4*)(B + (size_t)(k0 + bk) * DMODEL + n0 + bn);
    __syncthreads();
    As_t[ak + 0][ar] = av.x; As_t[ak + 1][ar] = av.y;
    As_t[ak + 2][ar] = av.z; As_t[ak + 3][ar] = av.w;
    *(float4*)&Bs[bk][bn] = bv;
    __syncthreads();
    GEMM_TILE_K16();
  }
#pragma unroll
  for (int i = 0; i < 4; ++i) {
    float4 v = {acc[i][0], acc[i][1], acc[i][2], acc[i][3]};
    *(float4*)(C + (size_t)(m0 + ty * 4 + i) * DMODEL + n0 + tx * 4) = v;
  }
}

// ---------- NT GEMM: C[M,Nout] = A[M,K] @ Bw[Nout,K]^T + epilogue ----------
// EP==0: + bias + addv + addm ; EP==1: + bias   (all fp32)
template <int EP>
__global__ __launch_bounds__(256) void k_gemm_nt(
    const float* __restrict__ A, const float* __restrict__ Bw,
    const float* __restrict__ bias, const float* __restrict__ addv,
    const float* __restrict__ addm, float* __restrict__ C, int K, int Nout) {
  const int m0 = blockIdx.x * 64, n0 = blockIdx.y * 64;
  __shared__ float As_t[16][68];
  __shared__ float Bs[16][68];
  const int t = threadIdx.x;
  const int tx = t & 15, ty = t >> 4;
  const int ar = t >> 2, ak = (t & 3) * 4;
  const int br = t >> 2, bkl = (t & 3) * 4;
  float acc[4][4] = {};
  for (int k0 = 0; k0 < K; k0 += 16) {
    const float4 av = *(const float4*)(A + (size_t)(m0 + ar) * K + k0 + ak);
    const float4 bv = *(const float4*)(Bw + (size_t)(n0 + br) * K + k0 + bkl);
    __syncthreads();
    As_t[ak + 0][ar] = av.x; As_t[ak + 1][ar] = av.y;
    As_t[ak + 2][ar] = av.z; As_t[ak + 3][ar] = av.w;
    Bs[bkl + 0][br] = bv.x; Bs[bkl + 1][br] = bv.y;
    Bs[bkl + 2][br] = bv.z; Bs[bkl + 3][br] = bv.w;
    __syncthreads();
    GEMM_TILE_K16();
  }
#pragma unroll
  for (int i = 0; i < 4; ++i) {
    const int r = m0 + ty * 4 + i;
    const int c = n0 + tx * 4;
    float4 v = {acc[i][0], acc[i][1], acc[i][2], acc[i][3]};
    const float4 bb = *(const float4*)(bias + c);
    v.x += bb.x; v.y += bb.y; v.z += bb.z; v.w += bb.w;
    if (EP == 0) {
      const float4 rv = *(const float4*)(addv + c);
      const float4 xv = *(const float4*)(addm + (size_t)r * Nout + c);
      v.x += rv.x + xv.x; v.y += rv.y + xv.y;
      v.z += rv.z + xv.z; v.w += rv.w + xv.w;
    }
    *(float4*)(C + (size_t)r * Nout + c) = v;
  }
}

// ---------------- Flash attention (fp32 qkv) -------------------------------
__global__ __launch_bounds__(256) void k_attn(const float* __restrict__ qkv,
                                              float* __restrict__ oatt) {
  const int q0 = blockIdx.x * 64, h = blockIdx.y, b = blockIdx.z;
  const int t = threadIdx.x;
  __shared__ float Qs[64][68];
  __shared__ float Ks[32][68];
  __shared__ float Vs[32][68];
  __shared__ float Ps[64][36];
  __shared__ float mrow[64], lrow[64];
  {
    const int qr = t >> 2, dl = (t & 3) * 16;
    const float* src =
        qkv + (size_t)(b * NSEQ + q0 + qr) * (3 * DMODEL) + h * HDIM + dl;
#pragma unroll
    for (int qq = 0; qq < 4; ++qq) {
      float4 v = *(const float4*)(src + qq * 4);
      v.x *= 0.125f; v.y *= 0.125f; v.z *= 0.125f; v.w *= 0.125f;
      *(float4*)&Qs[qr][dl + qq * 4] = v;
    }
    if (t < 64) { mrow[t] = -1e30f; lrow[t] = 0.f; }
  }
  float oacc[16] = {};
  const int orow = t >> 2, oc0 = (t & 3) * 16;
  const int sr = t >> 2, jb = t & 3;
  const int kr = t >> 3, kd = (t & 7) * 8;
  for (int k0 = 0; k0 < NSEQ; k0 += 32) {
    __syncthreads();
    {
      const float* kp =
          qkv + (size_t)(b * NSEQ + k0 + kr) * (3 * DMODEL) + DMODEL + h * HDIM + kd;
      const float4 ka = *(const float4*)kp;
      const float4 kb2 = *(const float4*)(kp + 4);
      const float4 va = *(const float4*)(kp + DMODEL);
      const float4 vb = *(const float4*)(kp + DMODEL + 4);
      *(float4*)&Ks[kr][kd] = ka;
      *(float4*)&Ks[kr][kd + 4] = kb2;
      *(float4*)&Vs[kr][kd] = va;
      *(float4*)&Vs[kr][kd + 4] = vb;
    }
    __syncthreads();
    float s[8];
#pragma unroll
    for (int j = 0; j < 8; ++j) s[j] = 0.f;
    const float4* Qs4 = (const float4*)&Qs[0][0];
    const float4* Ks4 = (const float4*)&Ks[0][0];
#pragma unroll 4
    for (int kk4 = 0; kk4 < 16; ++kk4) {
      const float4 qv = Qs4[sr * 17 + kk4];
#pragma unroll
      for (int jj = 0; jj < 8; ++jj) {
        const float4 kv = Ks4[(jb + 4 * jj) * 17 + kk4];
        s[jj] = fmaf(qv.x, kv.x, s[jj]);
        s[jj] = fmaf(qv.y, kv.y, s[jj]);
        s[jj] = fmaf(qv.z, kv.z, s[jj]);
        s[jj] = fmaf(qv.w, kv.w, s[jj]);
      }
    }
    float lmax = s[0];
#pragma unroll
    for (int j = 1; j < 8; ++j) lmax = fmaxf(lmax, s[j]);
    lmax = fmaxf(lmax, __shfl_xor(lmax, 1));
    lmax = fmaxf(lmax, __shfl_xor(lmax, 2));
    const float mold = mrow[sr];
    const float mnew = fmaxf(mold, lmax);
    float psum = 0.f;
#pragma unroll
    for (int jj = 0; jj < 8; ++jj) {
      const float p = __expf(s[jj] - mnew);
      Ps[sr][jb + 4 * jj] = p;
      psum += p;
    }
    psum += __shfl_xor(psum, 1);
    psum += __shfl_xor(psum, 2);
    const float alpha = __expf(mold - mnew);
    if ((t & 3) == 0) {
      mrow[sr] = mnew;
      lrow[sr] = lrow[sr] * alpha + psum;
    }
#pragma unroll
    for (int c = 0; c < 16; ++c) oacc[c] *= alpha;
    const float4* Vs4 = (const float4*)&Vs[0][0];
#pragma unroll 4
    for (int j = 0; j < 32; ++j) {
      const float p = Ps[orow][j];
#pragma unroll
      for (int c4 = 0; c4 < 4; ++c4) {
        const float4 vv = Vs4[j * 17 + (oc0 >> 2) + c4];
        oacc[c4 * 4 + 0] = fmaf(p, vv.x, oacc[c4 * 4 + 0]);
        oacc[c4 * 4 + 1] = fmaf(p, vv.y, oacc[c4 * 4 + 1]);
        oacc[c4 * 4 + 2] = fmaf(p, vv.z, oacc[c4 * 4 + 2]);
        oacc[c4 * 4 + 3] = fmaf(p, vv.w, oacc[c4 * 4 + 3]);
      }
    }
  }
  const float invl = 1.0f / lrow[orow];
  float* dst = oatt + (size_t)(b * NSEQ + q0 + orow) * DMODEL + h * HDIM + oc0;
#pragma unroll
  for (int c4 = 0; c4 < 4; ++c4) {
    float4 v = {oacc[c4 * 4 + 0] * invl, oacc[c4 * 4 + 1] * invl,
                oacc[c4 * 4 + 2] * invl, oacc[c4 * 4 + 3] * invl};
    *(float4*)(dst + c4 * 4) = v;
  }
}

// ---------------- LayerNorm( a + b ) -> x2 (f32) + x2b (bf16) --------------
__global__ __launch_bounds__(256) void k_ln_add(
    const float* __restrict__ a, const float* __restrict__ bsrc,
    const float* __restrict__ g, const float* __restrict__ be,
    float* __restrict__ outp, u16* __restrict__ outb) {
  const int tok = blockIdx.x;
  const int t = threadIdx.x;
  float2 v;
  {
    const float2 va = *(const float2*)(a + (size_t)tok * DMODEL + t * 2);
    const float2 vb = *(const float2*)(bsrc + (size_t)tok * DMODEL + t * 2);
    v.x = va.x + vb.x; v.y = va.y + vb.y;
  }
  float s1 = v.x + v.y, s2 = v.x * v.x + v.y * v.y;
#pragma unroll
  for (int o = 32; o; o >>= 1) { s1 += __shfl_down(s1, o); s2 += __shfl_down(s2, o); }
  __shared__ float sm1[4], sm2[4];
  if ((t & 63) == 0) { sm1[t >> 6] = s1; sm2[t >> 6] = s2; }
  __syncthreads();
  s1 = sm1[0] + sm1[1] + sm1[2] + sm1[3];
  s2 = sm2[0] + sm2[1] + sm2[2] + sm2[3];
  const float mean = s1 * (1.f / DMODEL);
  const float var = s2 * (1.f / DMODEL) - mean * mean;
  const float rstd = rsqrtf(var + 1e-5f);
  float2 o;
  o.x = (v.x - mean) * rstd * g[t * 2] + be[t * 2];
  o.y = (v.y - mean) * rstd * g[t * 2 + 1] + be[t * 2 + 1];
  *(float2*)(outp + (size_t)tok * DMODEL + t * 2) = o;
  ushort2 ob;
  ob.x = f2b(o.x); ob.y = f2b(o.y);
  *(ushort2*)(outb + (size_t)tok * DMODEL + t * 2) = ob;
}

// ---------------- MoE gating (fp32 x2) -------------------------------------
__global__ __launch_bounds__(256) void k_gate(const float* __restrict__ x2,
                                              const float* __restrict__ gw,
                                              int* __restrict__ eidx,
                                              float* __restrict__ ewgt,
                                              int* __restrict__ ecnt) {
  const int tok = blockIdx.x * 256 + threadIdx.x;
  float lg[NEXP] = {};
  const float* px = x2 + (size_t)tok * DMODEL;
  for (int i = 0; i < DMODEL; i += 4) {
    const float4 xv = *(const float4*)(px + i);
#pragma unroll
    for (int e = 0; e < NEXP; ++e) {
      const float4 wv = *(const float4*)(gw + e * DMODEL + i);
      lg[e] += xv.x * wv.x + xv.y * wv.y + xv.z * wv.z + xv.w * wv.w;
    }
  }
  int i0 = 0; float b0 = lg[0];
#pragma unroll
  for (int e = 1; e < NEXP; ++e) if (lg[e] > b0) { b0 = lg[e]; i0 = e; }
  int i1 = -1; float v1 = -1e30f;
#pragma unroll
  for (int e = 0; e < NEXP; ++e)
    if (e != i0 && lg[e] > v1) { v1 = lg[e]; i1 = e; }
  const float tt = __expf(v1 - b0);
  const float w0 = 1.f / (1.f + tt), w1 = tt / (1.f + tt);
  eidx[tok * 2] = i0; eidx[tok * 2 + 1] = i1;
  ewgt[tok * 2] = w0; ewgt[tok * 2 + 1] = w1;
  atomicAdd(&ecnt[i0], 1);
  atomicAdd(&ecnt[i1], 1);
}

__global__ void k_zero(int* __restrict__ p, int n) {
  const int i = blockIdx.x * blockDim.x + threadIdx.x;
  if (i < n) p[i] = 0;
}

__global__ void k_offsets(const int* __restrict__ ecnt, int* __restrict__ eoff) {
  if (threadIdx.x == 0) {
    int s = 0;
    for (int e = 0; e < NEXP; ++e) { eoff[e] = s; s += ecnt[e]; }
  }
}

__global__ __launch_bounds__(256) void k_scatter(
    const int* __restrict__ eidx, const int* __restrict__ eoff,
    int* __restrict__ efill, int* __restrict__ rtok, int* __restrict__ t2s) {
  const int tok = blockIdx.x * 256 + threadIdx.x;
#pragma unroll
  for (int k = 0; k < 2; ++k) {
    const int e = eidx[tok * 2 + k];
    const int pos = atomicAdd(&efill[e], 1);
    const int slot = eoff[e] + pos;
    rtok[slot] = tok;
    t2s[tok * 2 + k] = slot;
  }
}

// ------------- transpose-convert f32 [R][C] -> bf16 [C][R], per expert -----
__global__ __launch_bounds__(256) void k_cvt_t(const float* __restrict__ src,
                                               u16* __restrict__ dst,
                                               int R, int C) {
  const int e = blockIdx.z;
  src += (size_t)e * R * C;
  dst += (size_t)e * R * C;
  const int r0 = blockIdx.y * 64, c0 = blockIdx.x * 64;
  __shared__ u16 tile[64][65];
  const int t = threadIdx.x;
  const int cc = t & 63, rb = t >> 6;
#pragma unroll
  for (int i = 0; i < 16; ++i) {
    const int r = i * 4 + rb;
    tile[r][cc] = f2b(src[(size_t)(r0 + r) * C + c0 + cc]);
  }
  __syncthreads();
#pragma unroll
  for (int i = 0; i < 16; ++i) {
    const int r = i * 4 + rb;
    dst[(size_t)(c0 + r) * R + r0 + cc] = tile[cc][r];
  }
}

// ------------- MoE MFMA GEMM, 128x128 tile, BK=64, 4 waves (2x2) -----------
// MODE 0: hid[slot] = gelu(x2b[rtok[slot]] @ W1b[e]^T + b1[e])   K=512 N=2048
// MODE 1: ybuf[slot] = hid[slot] @ W2b[e]^T + b2[e]              K=2048 N=512
template <int MODE>
__global__ __launch_bounds__(256) void k_moe_mfma(
    const u16* __restrict__ Ab, const u16* __restrict__ Bb,
    const float* __restrict__ bias, const int* __restrict__ rtok,
    const int* __restrict__ ecnt, const int* __restrict__ eoff,
    u16* __restrict__ outp) {
  constexpr int K = (MODE == 0) ? DMODEL : DF;
  constexpr int N = (MODE == 0) ? DF : DMODEL;
  const int e = blockIdx.z;
  const int cnt = ecnt[e];
  const int m0 = blockIdx.y * 128;
  if (m0 >= cnt) return;
  const int off = eoff[e];
  const int n0 = blockIdx.x * 128;
  const u16* Bw = Bb + (size_t)e * (size_t)K * N;  // [N][K] bf16
  __shared__ u16 As[128][64];
  __shared__ u16 Bs[128][64];
  const int t = threadIdx.x;
  const int w = t >> 6, l = t & 63;
  const int srow = w * 8 + (l >> 3);   // +i*32 -> staged row
  const int scol = (l & 7) * 8;        // staged col (bf16)
  const u16* arow[4];
#pragma unroll
  for (int i = 0; i < 4; ++i) {
    const int r = m0 + i * 32 + srow;
    const int rr = (r < cnt) ? r : (cnt - 1);
    if (MODE == 0)
      arow[i] = Ab + (size_t)rtok[off + rr] * K + scol;
    else
      arow[i] = Ab + ((size_t)off + rr) * K + scol;
  }
  const u16* brow[4];
#pragma unroll
  for (int i = 0; i < 4; ++i)
    brow[i] = Bw + (size_t)(n0 + i * 32 + srow) * K + scol;

  const int wr = w >> 1, wc = w & 1;   // wave tile (64x64) coords
  const int lr = l & 15, lg = l >> 4;  // lane row / k-group
  f32x4_t acc[4][4] = {};
  for (int k0 = 0; k0 < K; k0 += 64) {
#pragma unroll
    for (int i = 0; i < 4; ++i) {
      gl_lds16(arow[i] + k0, &As[i * 32 + w * 8][0]);
      gl_lds16(brow[i] + k0, &Bs[i * 32 + w * 8][0]);
    }
    __syncthreads();  // drains vmcnt: tiles staged
#pragma unroll
    for (int kk = 0; kk < 2; ++kk) {
      bf16x8_t af[4], bfr[4];
#pragma unroll
      for (int m = 0; m < 4; ++m)
        af[m] = *(const bf16x8_t*)&As[wr * 64 + m * 16 + lr][kk * 32 + lg * 8];
#pragma unroll
      for (int n = 0; n < 4; ++n)
        bfr[n] = *(const bf16x8_t*)&Bs[wc * 64 + n * 16 + lr][kk * 32 + lg * 8];
#pragma unroll
      for (int m = 0; m < 4; ++m)
#pragma unroll
        for (int n = 0; n < 4; ++n)
          acc[m][n] = __builtin_amdgcn_mfma_f32_16x16x32_bf16(
              af[m], bfr[n], acc[m][n], 0, 0, 0);
    }
    __syncthreads();  // all reads done before next stage
  }
#pragma unroll
  for (int m = 0; m < 4; ++m) {
    const int rl0 = wr * 64 + m * 16 + lg * 4;
#pragma unroll
    for (int n = 0; n < 4; ++n) {
      const int gc = n0 + wc * 64 + n * 16 + lr;
      const float bv = bias[e * N + gc];
#pragma unroll
      for (int j = 0; j < 4; ++j) {
        const int r = m0 + rl0 + j;
        if (r < cnt) {
          float v = acc[m][n][j] + bv;
          if (MODE == 0) v = v * 0.5f * (1.f + erff(v * 0.70710678118f));
          outp[((size_t)off + r) * N + gc] = f2b(v);
        }
      }
    }
  }
}

// -------- combine: out = LN( x2 + w0*y[s0] + w1*y[s1] ), y in bf16 ---------
__global__ __launch_bounds__(256) void k_ln2(
    const float* __restrict__ x2, const u16* __restrict__ ybuf,
    const int* __restrict__ t2s, const float* __restrict__ ewgt,
    const float* __restrict__ g, const float* __restrict__ be,
    float* __restrict__ outp) {
  const int tok = blockIdx.x;
  const int t = threadIdx.x;
  const int s0 = t2s[tok * 2], s1i = t2s[tok * 2 + 1];
  const float w0 = ewgt[tok * 2], w1 = ewgt[tok * 2 + 1];
  float2 v;
  {
    const float2 a = *(const float2*)(x2 + (size_t)tok * DMODEL + t * 2);
    const ushort2 y0 = *(const ushort2*)(ybuf + (size_t)s0 * DMODEL + t * 2);
    const ushort2 y1 = *(const ushort2*)(ybuf + (size_t)s1i * DMODEL + t * 2);
    v.x = a.x + w0 * b2f(y0.x) + w1 * b2f(y1.x);
    v.y = a.y + w0 * b2f(y0.y) + w1 * b2f(y1.y);
  }
  float sum1 = v.x + v.y, sum2 = v.x * v.x + v.y * v.y;
#pragma unroll
  for (int o = 32; o; o >>= 1) { sum1 += __shfl_down(sum1, o); sum2 += __shfl_down(sum2, o); }
  __shared__ float sm1[4], sm2[4];
  if ((t & 63) == 0) { sm1[t >> 6] = sum1; sm2[t >> 6] = sum2; }
  __syncthreads();
  sum1 = sm1[0] + sm1[1] + sm1[2] + sm1[3];
  sum2 = sm2[0] + sm2[1] + sm2[2] + sm2[3];
  const float mean = sum1 * (1.f / DMODEL);
  const float var = sum2 * (1.f / DMODEL) - mean * mean;
  const float rstd = rsqrtf(var + 1e-5f);
  float2 o;
  o.x = (v.x - mean) * rstd * g[t * 2] + be[t * 2];
  o.y = (v.y - mean) * rstd * g[t * 2 + 1] + be[t * 2 + 1];
  *(float2*)(outp + (size_t)tok * DMODEL + t * 2) = o;
}

extern "C" void kernel_launch(void* const* d_in, const int* in_sizes, int n_in,
                              void* d_out, int out_size, void* d_ws,
                              size_t ws_size, hipStream_t stream) {
  const float* x      = (const float*)d_in[0];
  const float* adj    = (const float*)d_in[1];
  const float* gc_w   = (const float*)d_in[2];
  const float* gc_b   = (const float*)d_in[3];
  const float* root   = (const float*)d_in[4];
  const float* in_w   = (const float*)d_in[5];
  const float* in_b   = (const float*)d_in[6];
  const float* out_w  = (const float*)d_in[7];
  const float* out_b  = (const float*)d_in[8];
  const float* ln1_g  = (const float*)d_in[9];
  const float* ln1_b  = (const float*)d_in[10];
  const float* ln2_g  = (const float*)d_in[11];
  const float* ln2_b  = (const float*)d_in[12];
  const float* gate_w = (const float*)d_in[13];
  const float* W1     = (const float*)d_in[14];
  const float* b1     = (const float*)d_in[15];
  const float* W2     = (const float*)d_in[16];
  const float* b2     = (const float*)d_in[17];
  float* outp = (float*)d_out;

  // ws layout, peak 112.3 MB (== round-1 proven footprint). Lifetimes:
  //  [0,16)   ax -> oproj (dead after LN1) -> ybuf (moe2 -> ln2)
  //  [16,80)  hid (64MB, moe1->moe2); overlaps oatt[16,32) (dead after oproj),
  //           x1[32,48) (dead after LN1), qkv[48,80) head (dead after attn)
  //  [48,96)  qkv fp32 (gemmC -> attn); tail [80,96) becomes W1b then W2b
  //  [96,112) x2 fp32 (LN1 -> ln2)
  //  [112,..) misc routing arrays
  //  x2b (bf16, 8MB) lives in d_out[0,8MB) — dead before ln2 overwrites out.
  constexpr size_t MB = 1ull << 20;
  char* W = (char*)d_ws;
  float* ax    = (float*)(W + 0);
  float* oproj = ax;
  float* oatt  = (float*)(W + 16 * MB);
  float* x1    = (float*)(W + 32 * MB);
  float* qkv   = (float*)(W + 48 * MB);
  u16*   Wxb   = (u16*)(W + 80 * MB);   // W1b, then W2b
  float* x2    = (float*)(W + 96 * MB);
  char*  misc  = W + 112 * MB;
  u16*   hid   = (u16*)(W + 16 * MB);
  u16*   ybuf  = (u16*)(W + 0);
  u16*   x2b   = (u16*)d_out;            // scratch inside d_out
  int*   eidx  = (int*)misc;
  float* ewgt  = (float*)(misc + 65536);
  int*   ecnt  = (int*)(misc + 131072);
  int*   eoff  = (int*)(misc + 131072 + 128);
  int*   efill = (int*)(misc + 131072 + 256);
  int*   rtok  = (int*)(misc + 131072 + 512);
  int*   t2s   = (int*)(misc + 131072 + 512 + 65536);

  // A: ax = adj @ x
  k_adjx<<<dim3(16, 8, 8), 256, 0, stream>>>(adj, x, ax);
  // B: x1 = x + ax @ gc_w^T + gc_b + root_emb
  k_gemm_nt<0><<<dim3(128, 8), 256, 0, stream>>>(ax, gc_w, gc_b, root, x, x1,
                                                 DMODEL, DMODEL);
  // C: qkv = x1 @ in_w^T + in_b  (fp32)
  k_gemm_nt<1><<<dim3(128, 24), 256, 0, stream>>>(x1, in_w, in_b, nullptr,
                                                  nullptr, qkv, DMODEL,
                                                  3 * DMODEL);
  // D: attention (fp32)
  k_attn<<<dim3(16, 8, 8), 256, 0, stream>>>(qkv, oatt);
  // qkv now dead -> convert W1 into its tail region
  k_cvt_t<<<dim3(DF / 64, DMODEL / 64, NEXP), 256, 0, stream>>>(W1, Wxb,
                                                                DMODEL, DF);
  // E: oproj = oatt @ out_w^T + out_b
  k_gemm_nt<1><<<dim3(128, 8), 256, 0, stream>>>(oatt, out_w, out_b, nullptr,
                                                 nullptr, oproj, DMODEL,
                                                 DMODEL);
  // LN1: x2 (f32) + x2b (bf16, in d_out scratch)
  k_ln_add<<<dim3(T_TOK), 256, 0, stream>>>(x1, oproj, ln1_g, ln1_b, x2, x2b);
  // MoE routing (fp32 gate — keeps top-2 decisions reference-exact)
  k_zero<<<dim3(1), 128, 0, stream>>>((int*)(misc + 131072), 128);
  k_gate<<<dim3(T_TOK / 256), 256, 0, stream>>>(x2, gate_w, eidx, ewgt, ecnt);
  k_offsets<<<dim3(1), 64, 0, stream>>>(ecnt, eoff);
  k_scatter<<<dim3(T_TOK / 256), 256, 0, stream>>>(eidx, eoff, efill, rtok, t2s);
  // MoE expert FFN (MFMA bf16)
  k_moe_mfma<0><<<dim3(DF / 128, 128, NEXP), 256, 0, stream>>>(
      x2b, Wxb, b1, rtok, ecnt, eoff, hid);
  // W1b dead -> convert W2 into the same region
  k_cvt_t<<<dim3(DMODEL / 64, DF / 64, NEXP), 256, 0, stream>>>(W2, Wxb, DF,
                                                                DMODEL);
  k_moe_mfma<1><<<dim3(DMODEL / 128, 128, NEXP), 256, 0, stream>>>(
      hid, Wxb, b2, rtok, ecnt, eoff, ybuf);
  // combine + LN2 -> out
  k_ln2<<<dim3(T_TOK), 256, 0, stream>>>(x2, ybuf, t2s, ewgt, ln2_g, ln2_b,
                                         outp);
}

// Round 4
// 1025.869 us; speedup vs baseline: 1.9763x; 1.2506x over previous
//
#include <hip/hip_runtime.h>
#include <hip/hip_bf16.h>

#define NB 8
#define NSEQ 1024
#define DMODEL 512
#define DF 2048
#define NEXP 8
#define NHEAD 8
#define HDIM 64
#define T_TOK (NB * NSEQ)

typedef unsigned short u16;
typedef float f32x4_t __attribute__((ext_vector_type(4)));
typedef __bf16 bf16x8_t __attribute__((ext_vector_type(8)));

__device__ __forceinline__ u16 f2b(float f) {
  __hip_bfloat16 h = __float2bfloat16(f);
  return *reinterpret_cast<u16*>(&h);
}
__device__ __forceinline__ float b2f(u16 u) {
  return __uint_as_float((unsigned)u << 16);
}
// async global->LDS, 16B per lane; lds ptr must be wave-uniform
__device__ __forceinline__ void gl_lds16(const u16* g, u16* l) {
  __builtin_amdgcn_global_load_lds(
      (const __attribute__((address_space(1))) unsigned int*)g,
      (__attribute__((address_space(3))) unsigned int*)l, 16, 0, 0);
}

// 16 FMAs of the 4x4 micro-tile, k-major LDS tiles As_t[16][68], Bs[16][68]
#define GEMM_TILE_K16()                                                        \
  _Pragma("unroll") for (int kk = 0; kk < 16; ++kk) {                          \
    const float4 a4 = *(const float4*)(&As_t[kk][ty * 4]);                     \
    const float4 b4 = *(const float4*)(&Bs[kk][tx * 4]);                       \
    acc[0][0] = fmaf(a4.x, b4.x, acc[0][0]);                                   \
    acc[0][1] = fmaf(a4.x, b4.y, acc[0][1]);                                   \
    acc[0][2] = fmaf(a4.x, b4.z, acc[0][2]);                                   \
    acc[0][3] = fmaf(a4.x, b4.w, acc[0][3]);                                   \
    acc[1][0] = fmaf(a4.y, b4.x, acc[1][0]);                                   \
    acc[1][1] = fmaf(a4.y, b4.y, acc[1][1]);                                   \
    acc[1][2] = fmaf(a4.y, b4.z, acc[1][2]);                                   \
    acc[1][3] = fmaf(a4.y, b4.w, acc[1][3]);                                   \
    acc[2][0] = fmaf(a4.z, b4.x, acc[2][0]);                                   \
    acc[2][1] = fmaf(a4.z, b4.y, acc[2][1]);                                   \
    acc[2][2] = fmaf(a4.z, b4.z, acc[2][2]);                                   \
    acc[2][3] = fmaf(a4.z, b4.w, acc[2][3]);                                   \
    acc[3][0] = fmaf(a4.w, b4.x, acc[3][0]);                                   \
    acc[3][1] = fmaf(a4.w, b4.y, acc[3][1]);                                   \
    acc[3][2] = fmaf(a4.w, b4.z, acc[3][2]);                                   \
    acc[3][3] = fmaf(a4.w, b4.w, acc[3][3]);                                   \
  }

// ---------------- Stage A: ax[b] = adj[b] @ x[b] ---------------------------
__global__ __launch_bounds__(256) void k_adjx(const float* __restrict__ adj,
                                              const float* __restrict__ x,
                                              float* __restrict__ outp) {
  const int b = blockIdx.z;
  const int m0 = blockIdx.x * 64, n0 = blockIdx.y * 64;
  const float* A = adj + (size_t)b * NSEQ * NSEQ;
  const float* B = x + (size_t)b * NSEQ * DMODEL;
  float* C = outp + (size_t)b * NSEQ * DMODEL;
  __shared__ float As_t[16][68];
  __shared__ float Bs[16][68];
  const int t = threadIdx.x;
  const int tx = t & 15, ty = t >> 4;
  const int ar = t >> 2, ak = (t & 3) * 4;
  const int bk = t >> 4, bn = (t & 15) * 4;
  float acc[4][4] = {};
  for (int k0 = 0; k0 < NSEQ; k0 += 16) {
    const float4 av = *(const float4*)(A + (size_t)(m0 + ar) * NSEQ + k0 + ak);
    const float4 bv = *(const float4*)(B + (size_t)(k0 + bk) * DMODEL + n0 + bn);
    __syncthreads();
    As_t[ak + 0][ar] = av.x; As_t[ak + 1][ar] = av.y;
    As_t[ak + 2][ar] = av.z; As_t[ak + 3][ar] = av.w;
    *(float4*)&Bs[bk][bn] = bv;
    __syncthreads();
    GEMM_TILE_K16();
  }
#pragma unroll
  for (int i = 0; i < 4; ++i) {
    float4 v = {acc[i][0], acc[i][1], acc[i][2], acc[i][3]};
    *(float4*)(C + (size_t)(m0 + ty * 4 + i) * DMODEL + n0 + tx * 4) = v;
  }
}

// ---------- NT GEMM: C[M,Nout] = A[M,K] @ Bw[Nout,K]^T + epilogue ----------
template <int EP>
__global__ __launch_bounds__(256) void k_gemm_nt(
    const float* __restrict__ A, const float* __restrict__ Bw,
    const float* __restrict__ bias, const float* __restrict__ addv,
    const float* __restrict__ addm, float* __restrict__ C, int K, int Nout) {
  const int m0 = blockIdx.x * 64, n0 = blockIdx.y * 64;
  __shared__ float As_t[16][68];
  __shared__ float Bs[16][68];
  const int t = threadIdx.x;
  const int tx = t & 15, ty = t >> 4;
  const int ar = t >> 2, ak = (t & 3) * 4;
  const int br = t >> 2, bkl = (t & 3) * 4;
  float acc[4][4] = {};
  for (int k0 = 0; k0 < K; k0 += 16) {
    const float4 av = *(const float4*)(A + (size_t)(m0 + ar) * K + k0 + ak);
    const float4 bv = *(const float4*)(Bw + (size_t)(n0 + br) * K + k0 + bkl);
    __syncthreads();
    As_t[ak + 0][ar] = av.x; As_t[ak + 1][ar] = av.y;
    As_t[ak + 2][ar] = av.z; As_t[ak + 3][ar] = av.w;
    Bs[bkl + 0][br] = bv.x; Bs[bkl + 1][br] = bv.y;
    Bs[bkl + 2][br] = bv.z; Bs[bkl + 3][br] = bv.w;
    __syncthreads();
    GEMM_TILE_K16();
  }
#pragma unroll
  for (int i = 0; i < 4; ++i) {
    const int r = m0 + ty * 4 + i;
    const int c = n0 + tx * 4;
    float4 v = {acc[i][0], acc[i][1], acc[i][2], acc[i][3]};
    const float4 bb = *(const float4*)(bias + c);
    v.x += bb.x; v.y += bb.y; v.z += bb.z; v.w += bb.w;
    if (EP == 0) {
      const float4 rv = *(const float4*)(addv + c);
      const float4 xv = *(const float4*)(addm + (size_t)r * Nout + c);
      v.x += rv.x + xv.x; v.y += rv.y + xv.y;
      v.z += rv.z + xv.z; v.w += rv.w + xv.w;
    }
    *(float4*)(C + (size_t)r * Nout + c) = v;
  }
}

// -------- Flash attention, split-bf16 (hi/lo) MFMA, fp32-class accuracy ----
// Block: 64 q-rows, 4 waves (16 rows each). KV tiles of 64 rows.
// q*k = qh*kh + qh*kl + ql*kh (3 MFMAs); same for P*V. Error ~2^-17.
// LDS tiles [64][64] u16 with XOR swizzle: col ^= ((row&7)<<3).
__global__ __launch_bounds__(256) void k_attn(const float* __restrict__ qkv,
                                              float* __restrict__ oatt) {
  const int q0 = blockIdx.x * 64, h = blockIdx.y, b = blockIdx.z;
  const int t = threadIdx.x;
  const int w = t >> 6, l = t & 63;
  const int lr = l & 15, lg = l >> 4;
  __shared__ u16 Ksh[64][64], Ksl[64][64];
  __shared__ u16 Vth[64][64], Vtl[64][64];
  __shared__ u16 Psh[64][64], Psl[64][64];  // doubles as Q staging
  const int sr_ = t >> 2;          // staging row 0..63
  const int sc_ = (t & 3) * 16;    // staging col chunk
  // --- stage Q (scaled 1/8) into Ps region, split hi/lo, swizzled
  {
    const float* src =
        qkv + (size_t)(b * NSEQ + q0 + sr_) * (3 * DMODEL) + h * HDIM;
#pragma unroll
    for (int i = 0; i < 4; ++i) {
      float4 v = *(const float4*)(src + sc_ + i * 4);
      v.x *= 0.125f; v.y *= 0.125f; v.z *= 0.125f; v.w *= 0.125f;
      ushort4 h4, l4;
      h4.x = f2b(v.x); l4.x = f2b(v.x - b2f(h4.x));
      h4.y = f2b(v.y); l4.y = f2b(v.y - b2f(h4.y));
      h4.z = f2b(v.z); l4.z = f2b(v.z - b2f(h4.z));
      h4.w = f2b(v.w); l4.w = f2b(v.w - b2f(h4.w));
      const int cs = (sc_ + i * 4) ^ ((sr_ & 7) << 3);
      *(ushort4*)&Psh[sr_][cs] = h4;
      *(ushort4*)&Psl[sr_][cs] = l4;
    }
  }
  __syncthreads();
  // Q fragments -> registers (A-frag: row = w*16+lr, k = kc*32+lg*8)
  bf16x8_t qh[2], ql[2];
#pragma unroll
  for (int kc = 0; kc < 2; ++kc) {
    const int cs = (kc * 32 + lg * 8) ^ ((lr & 7) << 3);
    qh[kc] = *(const bf16x8_t*)&Psh[w * 16 + lr][cs];
    ql[kc] = *(const bf16x8_t*)&Psl[w * 16 + lr][cs];
  }
  float mrow[4] = {-1e30f, -1e30f, -1e30f, -1e30f};
  float lrow[4] = {0.f, 0.f, 0.f, 0.f};
  f32x4_t acc_o[4] = {};
  for (int k0 = 0; k0 < NSEQ; k0 += 64) {
    __syncthreads();  // prev PV/QK reads done before restaging
    // --- stage K rows + V transposed, split hi/lo
    {
      const float* kp =
          qkv + (size_t)(b * NSEQ + k0 + sr_) * (3 * DMODEL) + DMODEL + h * HDIM;
#pragma unroll
      for (int i = 0; i < 4; ++i) {
        float4 kv4 = *(const float4*)(kp + sc_ + i * 4);
        ushort4 h4, l4;
        h4.x = f2b(kv4.x); l4.x = f2b(kv4.x - b2f(h4.x));
        h4.y = f2b(kv4.y); l4.y = f2b(kv4.y - b2f(h4.y));
        h4.z = f2b(kv4.z); l4.z = f2b(kv4.z - b2f(h4.z));
        h4.w = f2b(kv4.w); l4.w = f2b(kv4.w - b2f(h4.w));
        const int cs = (sc_ + i * 4) ^ ((sr_ & 7) << 3);
        *(ushort4*)&Ksh[sr_][cs] = h4;
        *(ushort4*)&Ksl[sr_][cs] = l4;
      }
#pragma unroll
      for (int i = 0; i < 4; ++i) {
        const int d0 = (t & 3) * 4 + i * 16;
        const float4 vv4 = *(const float4*)(kp + DMODEL + d0);
#pragma unroll
        for (int jj = 0; jj < 4; ++jj) {
          const float f = (jj == 0) ? vv4.x : (jj == 1) ? vv4.y
                                   : (jj == 2) ? vv4.z : vv4.w;
          const u16 hi = f2b(f);
          const u16 lo = f2b(f - b2f(hi));
          const int d = d0 + jj;
          const int cs = sr_ ^ ((d & 7) << 3);
          Vth[d][cs] = hi;
          Vtl[d][cs] = lo;
        }
      }
    }
    __syncthreads();
    // --- S = Q K^T (split 3-term)
    f32x4_t sacc[4] = {};
#pragma unroll
    for (int kc = 0; kc < 2; ++kc) {
#pragma unroll
      for (int n = 0; n < 4; ++n) {
        const int cs = (kc * 32 + lg * 8) ^ ((lr & 7) << 3);
        const bf16x8_t kh = *(const bf16x8_t*)&Ksh[n * 16 + lr][cs];
        const bf16x8_t kl = *(const bf16x8_t*)&Ksl[n * 16 + lr][cs];
        sacc[n] = __builtin_amdgcn_mfma_f32_16x16x32_bf16(qh[kc], kh, sacc[n], 0, 0, 0);
        sacc[n] = __builtin_amdgcn_mfma_f32_16x16x32_bf16(qh[kc], kl, sacc[n], 0, 0, 0);
        sacc[n] = __builtin_amdgcn_mfma_f32_16x16x32_bf16(ql[kc], kh, sacc[n], 0, 0, 0);
      }
    }
    // --- online softmax; rows rq = lg*4+j live in 16-lane group (cols = lanes)
    float alpha[4];
#pragma unroll
    for (int j = 0; j < 4; ++j) {
      float mx = fmaxf(fmaxf(sacc[0][j], sacc[1][j]),
                       fmaxf(sacc[2][j], sacc[3][j]));
      mx = fmaxf(mx, __shfl_xor(mx, 1));
      mx = fmaxf(mx, __shfl_xor(mx, 2));
      mx = fmaxf(mx, __shfl_xor(mx, 4));
      mx = fmaxf(mx, __shfl_xor(mx, 8));
      const float mnew = fmaxf(mrow[j], mx);
      alpha[j] = __expf(mrow[j] - mnew);
      mrow[j] = mnew;
      float psum = 0.f;
      const int prow = lg * 4 + j;
#pragma unroll
      for (int n = 0; n < 4; ++n) {
        const float p = __expf(sacc[n][j] - mnew);
        psum += p;
        const u16 hi = f2b(p);
        const u16 lo = f2b(p - b2f(hi));
        const int pcol = (n * 16 + lr) ^ ((prow & 7) << 3);
        Psh[w * 16 + prow][pcol] = hi;
        Psl[w * 16 + prow][pcol] = lo;
      }
      psum += __shfl_xor(psum, 1);
      psum += __shfl_xor(psum, 2);
      psum += __shfl_xor(psum, 4);
      psum += __shfl_xor(psum, 8);
      lrow[j] = lrow[j] * alpha[j] + psum;
    }
#pragma unroll
    for (int n = 0; n < 4; ++n) {
#pragma unroll
      for (int j = 0; j < 4; ++j) acc_o[n][j] *= alpha[j];
    }
    // --- O += P V (split 3-term); Ps rows are wave-private (no barrier)
#pragma unroll
    for (int kc = 0; kc < 2; ++kc) {
      const int cs = (kc * 32 + lg * 8) ^ ((lr & 7) << 3);
      const bf16x8_t ph = *(const bf16x8_t*)&Psh[w * 16 + lr][cs];
      const bf16x8_t pl = *(const bf16x8_t*)&Psl[w * 16 + lr][cs];
#pragma unroll
      for (int n = 0; n < 4; ++n) {
        const bf16x8_t vh = *(const bf16x8_t*)&Vth[n * 16 + lr][cs];
        const bf16x8_t vl = *(const bf16x8_t*)&Vtl[n * 16 + lr][cs];
        acc_o[n] = __builtin_amdgcn_mfma_f32_16x16x32_bf16(ph, vh, acc_o[n], 0, 0, 0);
        acc_o[n] = __builtin_amdgcn_mfma_f32_16x16x32_bf16(ph, vl, acc_o[n], 0, 0, 0);
        acc_o[n] = __builtin_amdgcn_mfma_f32_16x16x32_bf16(pl, vh, acc_o[n], 0, 0, 0);
      }
    }
  }
  // --- epilogue: D rows = lg*4+j, cols = n*16+lr
#pragma unroll
  for (int j = 0; j < 4; ++j) {
    const float invl = 1.0f / lrow[j];
    float* dst =
        oatt + (size_t)(b * NSEQ + q0 + w * 16 + lg * 4 + j) * DMODEL + h * HDIM;
#pragma unroll
    for (int n = 0; n < 4; ++n) dst[n * 16 + lr] = acc_o[n][j] * invl;
  }
}

// ---------------- LayerNorm( a + b ) -> x2 (f32) + x2b (bf16) --------------
__global__ __launch_bounds__(256) void k_ln_add(
    const float* __restrict__ a, const float* __restrict__ bsrc,
    const float* __restrict__ g, const float* __restrict__ be,
    float* __restrict__ outp, u16* __restrict__ outb) {
  const int tok = blockIdx.x;
  const int t = threadIdx.x;
  float2 v;
  {
    const float2 va = *(const float2*)(a + (size_t)tok * DMODEL + t * 2);
    const float2 vb = *(const float2*)(bsrc + (size_t)tok * DMODEL + t * 2);
    v.x = va.x + vb.x; v.y = va.y + vb.y;
  }
  float s1 = v.x + v.y, s2 = v.x * v.x + v.y * v.y;
#pragma unroll
  for (int o = 32; o; o >>= 1) { s1 += __shfl_down(s1, o); s2 += __shfl_down(s2, o); }
  __shared__ float sm1[4], sm2[4];
  if ((t & 63) == 0) { sm1[t >> 6] = s1; sm2[t >> 6] = s2; }
  __syncthreads();
  s1 = sm1[0] + sm1[1] + sm1[2] + sm1[3];
  s2 = sm2[0] + sm2[1] + sm2[2] + sm2[3];
  const float mean = s1 * (1.f / DMODEL);
  const float var = s2 * (1.f / DMODEL) - mean * mean;
  const float rstd = rsqrtf(var + 1e-5f);
  float2 o;
  o.x = (v.x - mean) * rstd * g[t * 2] + be[t * 2];
  o.y = (v.y - mean) * rstd * g[t * 2 + 1] + be[t * 2 + 1];
  *(float2*)(outp + (size_t)tok * DMODEL + t * 2) = o;
  ushort2 ob;
  ob.x = f2b(o.x); ob.y = f2b(o.y);
  *(ushort2*)(outb + (size_t)tok * DMODEL + t * 2) = ob;
}

// ---------------- MoE gating (fp32 x2) -------------------------------------
__global__ __launch_bounds__(256) void k_gate(const float* __restrict__ x2,
                                              const float* __restrict__ gw,
                                              int* __restrict__ eidx,
                                              float* __restrict__ ewgt,
                                              int* __restrict__ ecnt) {
  const int tok = blockIdx.x * 256 + threadIdx.x;
  float lg[NEXP] = {};
  const float* px = x2 + (size_t)tok * DMODEL;
  for (int i = 0; i < DMODEL; i += 4) {
    const float4 xv = *(const float4*)(px + i);
#pragma unroll
    for (int e = 0; e < NEXP; ++e) {
      const float4 wv = *(const float4*)(gw + e * DMODEL + i);
      lg[e] += xv.x * wv.x + xv.y * wv.y + xv.z * wv.z + xv.w * wv.w;
    }
  }
  int i0 = 0; float b0 = lg[0];
#pragma unroll
  for (int e = 1; e < NEXP; ++e) if (lg[e] > b0) { b0 = lg[e]; i0 = e; }
  int i1 = -1; float v1 = -1e30f;
#pragma unroll
  for (int e = 0; e < NEXP; ++e)
    if (e != i0 && lg[e] > v1) { v1 = lg[e]; i1 = e; }
  const float tt = __expf(v1 - b0);
  const float w0 = 1.f / (1.f + tt), w1 = tt / (1.f + tt);
  eidx[tok * 2] = i0; eidx[tok * 2 + 1] = i1;
  ewgt[tok * 2] = w0; ewgt[tok * 2 + 1] = w1;
  atomicAdd(&ecnt[i0], 1);
  atomicAdd(&ecnt[i1], 1);
}

__global__ void k_zero(int* __restrict__ p, int n) {
  const int i = blockIdx.x * blockDim.x + threadIdx.x;
  if (i < n) p[i] = 0;
}

__global__ void k_offsets(const int* __restrict__ ecnt, int* __restrict__ eoff) {
  if (threadIdx.x == 0) {
    int s = 0;
    for (int e = 0; e < NEXP; ++e) { eoff[e] = s; s += ecnt[e]; }
  }
}

__global__ __launch_bounds__(256) void k_scatter(
    const int* __restrict__ eidx, const int* __restrict__ eoff,
    int* __restrict__ efill, int* __restrict__ rtok, int* __restrict__ t2s) {
  const int tok = blockIdx.x * 256 + threadIdx.x;
#pragma unroll
  for (int k = 0; k < 2; ++k) {
    const int e = eidx[tok * 2 + k];
    const int pos = atomicAdd(&efill[e], 1);
    const int slot = eoff[e] + pos;
    rtok[slot] = tok;
    t2s[tok * 2 + k] = slot;
  }
}

// ------------- transpose-convert f32 [R][C] -> bf16 [C][R], per expert -----
__global__ __launch_bounds__(256) void k_cvt_t(const float* __restrict__ src,
                                               u16* __restrict__ dst,
                                               int R, int C) {
  const int e = blockIdx.z;
  src += (size_t)e * R * C;
  dst += (size_t)e * R * C;
  const int r0 = blockIdx.y * 64, c0 = blockIdx.x * 64;
  __shared__ u16 tile[64][65];
  const int t = threadIdx.x;
  const int cc = t & 63, rb = t >> 6;
#pragma unroll
  for (int i = 0; i < 16; ++i) {
    const int r = i * 4 + rb;
    tile[r][cc] = f2b(src[(size_t)(r0 + r) * C + c0 + cc]);
  }
  __syncthreads();
#pragma unroll
  for (int i = 0; i < 16; ++i) {
    const int r = i * 4 + rb;
    dst[(size_t)(c0 + r) * R + r0 + cc] = tile[cc][r];
  }
}

// ------------- MoE MFMA GEMM, 128x128 tile, BK=64, 4 waves (2x2) -----------
template <int MODE>
__global__ __launch_bounds__(256) void k_moe_mfma(
    const u16* __restrict__ Ab, const u16* __restrict__ Bb,
    const float* __restrict__ bias, const int* __restrict__ rtok,
    const int* __restrict__ ecnt, const int* __restrict__ eoff,
    u16* __restrict__ outp) {
  constexpr int K = (MODE == 0) ? DMODEL : DF;
  constexpr int N = (MODE == 0) ? DF : DMODEL;
  const int e = blockIdx.z;
  const int cnt = ecnt[e];
  const int m0 = blockIdx.y * 128;
  if (m0 >= cnt) return;
  const int off = eoff[e];
  const int n0 = blockIdx.x * 128;
  const u16* Bw = Bb + (size_t)e * (size_t)K * N;  // [N][K] bf16
  __shared__ u16 As[128][64];
  __shared__ u16 Bs[128][64];
  const int t = threadIdx.x;
  const int w = t >> 6, l = t & 63;
  const int srow = w * 8 + (l >> 3);
  const int scol = (l & 7) * 8;
  const u16* arow[4];
#pragma unroll
  for (int i = 0; i < 4; ++i) {
    const int r = m0 + i * 32 + srow;
    const int rr = (r < cnt) ? r : (cnt - 1);
    if (MODE == 0)
      arow[i] = Ab + (size_t)rtok[off + rr] * K + scol;
    else
      arow[i] = Ab + ((size_t)off + rr) * K + scol;
  }
  const u16* brow[4];
#pragma unroll
  for (int i = 0; i < 4; ++i)
    brow[i] = Bw + (size_t)(n0 + i * 32 + srow) * K + scol;

  const int wr = w >> 1, wc = w & 1;
  const int lr = l & 15, lg = l >> 4;
  f32x4_t acc[4][4] = {};
  for (int k0 = 0; k0 < K; k0 += 64) {
#pragma unroll
    for (int i = 0; i < 4; ++i) {
      gl_lds16(arow[i] + k0, &As[i * 32 + w * 8][0]);
      gl_lds16(brow[i] + k0, &Bs[i * 32 + w * 8][0]);
    }
    __syncthreads();
#pragma unroll
    for (int kk = 0; kk < 2; ++kk) {
      bf16x8_t af[4], bfr[4];
#pragma unroll
      for (int m = 0; m < 4; ++m)
        af[m] = *(const bf16x8_t*)&As[wr * 64 + m * 16 + lr][kk * 32 + lg * 8];
#pragma unroll
      for (int n = 0; n < 4; ++n)
        bfr[n] = *(const bf16x8_t*)&Bs[wc * 64 + n * 16 + lr][kk * 32 + lg * 8];
#pragma unroll
      for (int m = 0; m < 4; ++m)
#pragma unroll
        for (int n = 0; n < 4; ++n)
          acc[m][n] = __builtin_amdgcn_mfma_f32_16x16x32_bf16(
              af[m], bfr[n], acc[m][n], 0, 0, 0);
    }
    __syncthreads();
  }
#pragma unroll
  for (int m = 0; m < 4; ++m) {
    const int rl0 = wr * 64 + m * 16 + lg * 4;
#pragma unroll
    for (int n = 0; n < 4; ++n) {
      const int gc = n0 + wc * 64 + n * 16 + lr;
      const float bv = bias[e * N + gc];
#pragma unroll
      for (int j = 0; j < 4; ++j) {
        const int r = m0 + rl0 + j;
        if (r < cnt) {
          float v = acc[m][n][j] + bv;
          if (MODE == 0) v = v * 0.5f * (1.f + erff(v * 0.70710678118f));
          outp[((size_t)off + r) * N + gc] = f2b(v);
        }
      }
    }
  }
}

// -------- combine: out = LN( x2 + w0*y[s0] + w1*y[s1] ), y in bf16 ---------
__global__ __launch_bounds__(256) void k_ln2(
    const float* __restrict__ x2, const u16* __restrict__ ybuf,
    const int* __restrict__ t2s, const float* __restrict__ ewgt,
    const float* __restrict__ g, const float* __restrict__ be,
    float* __restrict__ outp) {
  const int tok = blockIdx.x;
  const int t = threadIdx.x;
  const int s0 = t2s[tok * 2], s1i = t2s[tok * 2 + 1];
  const float w0 = ewgt[tok * 2], w1 = ewgt[tok * 2 + 1];
  float2 v;
  {
    const float2 a = *(const float2*)(x2 + (size_t)tok * DMODEL + t * 2);
    const ushort2 y0 = *(const ushort2*)(ybuf + (size_t)s0 * DMODEL + t * 2);
    const ushort2 y1 = *(const ushort2*)(ybuf + (size_t)s1i * DMODEL + t * 2);
    v.x = a.x + w0 * b2f(y0.x) + w1 * b2f(y1.x);
    v.y = a.y + w0 * b2f(y0.y) + w1 * b2f(y1.y);
  }
  float sum1 = v.x + v.y, sum2 = v.x * v.x + v.y * v.y;
#pragma unroll
  for (int o = 32; o; o >>= 1) { sum1 += __shfl_down(sum1, o); sum2 += __shfl_down(sum2, o); }
  __shared__ float sm1[4], sm2[4];
  if ((t & 63) == 0) { sm1[t >> 6] = sum1; sm2[t >> 6] = sum2; }
  __syncthreads();
  sum1 = sm1[0] + sm1[1] + sm1[2] + sm1[3];
  sum2 = sm2[0] + sm2[1] + sm2[2] + sm2[3];
  const float mean = sum1 * (1.f / DMODEL);
  const float var = sum2 * (1.f / DMODEL) - mean * mean;
  const float rstd = rsqrtf(var + 1e-5f);
  float2 o;
  o.x = (v.x - mean) * rstd * g[t * 2] + be[t * 2];
  o.y = (v.y - mean) * rstd * g[t * 2 + 1] + be[t * 2 + 1];
  *(float2*)(outp + (size_t)tok * DMODEL + t * 2) = o;
}

extern "C" void kernel_launch(void* const* d_in, const int* in_sizes, int n_in,
                              void* d_out, int out_size, void* d_ws,
                              size_t ws_size, hipStream_t stream) {
  const float* x      = (const float*)d_in[0];
  const float* adj    = (const float*)d_in[1];
  const float* gc_w   = (const float*)d_in[2];
  const float* gc_b   = (const float*)d_in[3];
  const float* root   = (const float*)d_in[4];
  const float* in_w   = (const float*)d_in[5];
  const float* in_b   = (const float*)d_in[6];
  const float* out_w  = (const float*)d_in[7];
  const float* out_b  = (const float*)d_in[8];
  const float* ln1_g  = (const float*)d_in[9];
  const float* ln1_b  = (const float*)d_in[10];
  const float* ln2_g  = (const float*)d_in[11];
  const float* ln2_b  = (const float*)d_in[12];
  const float* gate_w = (const float*)d_in[13];
  const float* W1     = (const float*)d_in[14];
  const float* b1     = (const float*)d_in[15];
  const float* W2     = (const float*)d_in[16];
  const float* b2     = (const float*)d_in[17];
  float* outp = (float*)d_out;

  constexpr size_t MB = 1ull << 20;
  char* W = (char*)d_ws;
  float* ax    = (float*)(W + 0);
  float* oproj = ax;
  float* oatt  = (float*)(W + 16 * MB);
  float* x1    = (float*)(W + 32 * MB);
  float* qkv   = (float*)(W + 48 * MB);
  u16*   Wxb   = (u16*)(W + 80 * MB);   // W1b, then W2b
  float* x2    = (float*)(W + 96 * MB);
  char*  misc  = W + 112 * MB;
  u16*   hid   = (u16*)(W + 16 * MB);
  u16*   ybuf  = (u16*)(W + 0);
  u16*   x2b   = (u16*)d_out;            // scratch inside d_out
  int*   eidx  = (int*)misc;
  float* ewgt  = (float*)(misc + 65536);
  int*   ecnt  = (int*)(misc + 131072);
  int*   eoff  = (int*)(misc + 131072 + 128);
  int*   efill = (int*)(misc + 131072 + 256);
  int*   rtok  = (int*)(misc + 131072 + 512);
  int*   t2s   = (int*)(misc + 131072 + 512 + 65536);

  // A: ax = adj @ x
  k_adjx<<<dim3(16, 8, 8), 256, 0, stream>>>(adj, x, ax);
  // B: x1 = x + ax @ gc_w^T + gc_b + root_emb
  k_gemm_nt<0><<<dim3(128, 8), 256, 0, stream>>>(ax, gc_w, gc_b, root, x, x1,
                                                 DMODEL, DMODEL);
  // C: qkv = x1 @ in_w^T + in_b  (fp32)
  k_gemm_nt<1><<<dim3(128, 24), 256, 0, stream>>>(x1, in_w, in_b, nullptr,
                                                  nullptr, qkv, DMODEL,
                                                  3 * DMODEL);
  // D: attention (split-bf16 MFMA, fp32-class accuracy)
  k_attn<<<dim3(16, 8, 8), 256, 0, stream>>>(qkv, oatt);
  // qkv tail dead after attn -> convert W1 there
  k_cvt_t<<<dim3(DF / 64, DMODEL / 64, NEXP), 256, 0, stream>>>(W1, Wxb,
                                                                DMODEL, DF);
  // E: oproj = oatt @ out_w^T + out_b
  k_gemm_nt<1><<<dim3(128, 8), 256, 0, stream>>>(oatt, out_w, out_b, nullptr,
                                                 nullptr, oproj, DMODEL,
                                                 DMODEL);
  // LN1: x2 (f32) + x2b (bf16)
  k_ln_add<<<dim3(T_TOK), 256, 0, stream>>>(x1, oproj, ln1_g, ln1_b, x2, x2b);
  // MoE routing (fp32 gate)
  k_zero<<<dim3(1), 128, 0, stream>>>((int*)(misc + 131072), 128);
  k_gate<<<dim3(T_TOK / 256), 256, 0, stream>>>(x2, gate_w, eidx, ewgt, ecnt);
  k_offsets<<<dim3(1), 64, 0, stream>>>(ecnt, eoff);
  k_scatter<<<dim3(T_TOK / 256), 256, 0, stream>>>(eidx, eoff, efill, rtok, t2s);
  // MoE expert FFN (MFMA bf16)
  k_moe_mfma<0><<<dim3(DF / 128, 128, NEXP), 256, 0, stream>>>(
      x2b, Wxb, b1, rtok, ecnt, eoff, hid);
  k_cvt_t<<<dim3(DMODEL / 64, DF / 64, NEXP), 256, 0, stream>>>(W2, Wxb, DF,
                                                                DMODEL);
  k_moe_mfma<1><<<dim3(DMODEL / 128, 128, NEXP), 256, 0, stream>>>(
      hid, Wxb, b2, rtok, ecnt, eoff, ybuf);
  // combine + LN2 -> out
  k_ln2<<<dim3(T_TOK), 256, 0, stream>>>(x2, ybuf, t2s, ewgt, ln2_g, ln2_b,
                                         outp);
}

// Round 5
// 791.989 us; speedup vs baseline: 2.5599x; 1.2953x over previous
//
#include <hip/hip_runtime.h>
#include <hip/hip_bf16.h>

#define NB 8
#define NSEQ 1024
#define DMODEL 512
#define DF 2048
#define NEXP 8
#define NHEAD 8
#define HDIM 64
#define T_TOK (NB * NSEQ)

typedef unsigned short u16;
typedef float f32x4_t __attribute__((ext_vector_type(4)));
typedef __bf16 bf16x8_t __attribute__((ext_vector_type(8)));

__device__ __forceinline__ u16 f2b(float f) {
  __hip_bfloat16 h = __float2bfloat16(f);
  return *reinterpret_cast<u16*>(&h);
}
__device__ __forceinline__ float b2f(u16 u) {
  return __uint_as_float((unsigned)u << 16);
}
// async global->LDS, 16B per lane; lds ptr must be wave-uniform
__device__ __forceinline__ void gl_lds16(const u16* g, u16* l) {
  __builtin_amdgcn_global_load_lds(
      (const __attribute__((address_space(1))) unsigned int*)g,
      (__attribute__((address_space(3))) unsigned int*)l, 16, 0, 0);
}

// ---------------- elementwise conversions ----------------------------------
__global__ __launch_bounds__(256) void k_cvt_hl(const float* __restrict__ src,
                                                u16* __restrict__ hi,
                                                u16* __restrict__ lo, int n4) {
  const int i = blockIdx.x * 256 + threadIdx.x;
  if (i >= n4) return;
  const float4 v = ((const float4*)src)[i];
  ushort4 h, l;
  h.x = f2b(v.x); l.x = f2b(v.x - b2f(h.x));
  h.y = f2b(v.y); l.y = f2b(v.y - b2f(h.y));
  h.z = f2b(v.z); l.z = f2b(v.z - b2f(h.z));
  h.w = f2b(v.w); l.w = f2b(v.w - b2f(h.w));
  ((ushort4*)hi)[i] = h;
  ((ushort4*)lo)[i] = l;
}

__global__ __launch_bounds__(256) void k_cvt_b(const float* __restrict__ src,
                                               u16* __restrict__ dst, int n4) {
  const int i = blockIdx.x * 256 + threadIdx.x;
  if (i >= n4) return;
  const float4 v = ((const float4*)src)[i];
  ushort4 h;
  h.x = f2b(v.x); h.y = f2b(v.y); h.z = f2b(v.z); h.w = f2b(v.w);
  ((ushort4*)dst)[i] = h;
}

// transpose + split per batch: src [R][C] f32 -> hi/lo [C][R] bf16
__global__ __launch_bounds__(256) void k_cvt_t_hl(const float* __restrict__ src,
                                                  u16* __restrict__ hi,
                                                  u16* __restrict__ lo,
                                                  int R, int C) {
  const int z = blockIdx.z;
  src += (size_t)z * R * C;
  hi += (size_t)z * R * C;
  lo += (size_t)z * R * C;
  const int r0 = blockIdx.y * 64, c0 = blockIdx.x * 64;
  __shared__ u16 th[64][65], tl[64][65];
  const int t = threadIdx.x;
  const int cc = t & 63, rb = t >> 6;
#pragma unroll
  for (int i = 0; i < 16; ++i) {
    const int r = i * 4 + rb;
    const float f = src[(size_t)(r0 + r) * C + c0 + cc];
    const u16 h = f2b(f);
    th[r][cc] = h;
    tl[r][cc] = f2b(f - b2f(h));
  }
  __syncthreads();
#pragma unroll
  for (int i = 0; i < 16; ++i) {
    const int r = i * 4 + rb;
    hi[(size_t)(c0 + r) * R + r0 + cc] = th[cc][r];
    lo[(size_t)(c0 + r) * R + r0 + cc] = tl[cc][r];
  }
}

// ------- split-bf16 dense MFMA GEMM, 128x128 tile, BK=64, 4 waves ---------
// C = A @ B^T with A=Ah(+Al), B=Bh+Bl pre-split bf16 ([M][K], [N][K]).
// TERMS=3: ah*bh + ah*bl + al*bh ; TERMS=2 (A exact): ah*bh + ah*bl.
// EP: 0 = write hi/lo only; 1 = +bias+addv+addm, write F + hi/lo; 2 = +bias, F.
template <int TERMS, int EP>
__global__ __launch_bounds__(256) void k_gemm_sp(
    const u16* __restrict__ Ah, const u16* __restrict__ Al,
    const u16* __restrict__ Bh, const u16* __restrict__ Bl,
    const float* __restrict__ bias, const float* __restrict__ addv,
    const float* __restrict__ addm, float* __restrict__ outF,
    u16* __restrict__ outH, u16* __restrict__ outL, int K, int N,
    size_t aStride, size_t bStride, size_t cStride) {
  const int z = blockIdx.z;
  Ah += (size_t)z * aStride;
  if (TERMS == 3) Al += (size_t)z * aStride;
  Bh += (size_t)z * bStride;
  Bl += (size_t)z * bStride;
  const int m0 = blockIdx.y * 128, n0 = blockIdx.x * 128;
  __shared__ u16 Ash[128][64];
  __shared__ u16 Asl[(TERMS == 3) ? 128 : 1][64];
  __shared__ u16 Bsh[128][64];
  __shared__ u16 Bsl[128][64];
  const int t = threadIdx.x;
  const int w = t >> 6, l = t & 63;
  const int srow = w * 8 + (l >> 3);
  const int scol = (l & 7) * 8;
  size_t aoff[4], boff[4];
#pragma unroll
  for (int i = 0; i < 4; ++i) {
    aoff[i] = (size_t)(m0 + i * 32 + srow) * K + scol;
    boff[i] = (size_t)(n0 + i * 32 + srow) * K + scol;
  }
  const int wr = w >> 1, wc = w & 1;
  const int lr = l & 15, lg = l >> 4;
  f32x4_t acc[4][4] = {};
  for (int k0 = 0; k0 < K; k0 += 64) {
#pragma unroll
    for (int i = 0; i < 4; ++i) {
      gl_lds16(Ah + aoff[i] + k0, &Ash[i * 32 + w * 8][0]);
      if (TERMS == 3) gl_lds16(Al + aoff[i] + k0, &Asl[i * 32 + w * 8][0]);
      gl_lds16(Bh + boff[i] + k0, &Bsh[i * 32 + w * 8][0]);
      gl_lds16(Bl + boff[i] + k0, &Bsl[i * 32 + w * 8][0]);
    }
    __syncthreads();  // drains vmcnt: tiles staged
#pragma unroll
    for (int kk = 0; kk < 2; ++kk) {
      const int cs = kk * 32 + lg * 8;
      bf16x8_t ah[4], al[4], bh[4], bl[4];
#pragma unroll
      for (int m = 0; m < 4; ++m) {
        ah[m] = *(const bf16x8_t*)&Ash[wr * 64 + m * 16 + lr][cs];
        if (TERMS == 3)
          al[m] = *(const bf16x8_t*)&Asl[wr * 64 + m * 16 + lr][cs];
      }
#pragma unroll
      for (int n = 0; n < 4; ++n) {
        bh[n] = *(const bf16x8_t*)&Bsh[wc * 64 + n * 16 + lr][cs];
        bl[n] = *(const bf16x8_t*)&Bsl[wc * 64 + n * 16 + lr][cs];
      }
#pragma unroll
      for (int m = 0; m < 4; ++m)
#pragma unroll
        for (int n = 0; n < 4; ++n) {
          acc[m][n] = __builtin_amdgcn_mfma_f32_16x16x32_bf16(ah[m], bh[n],
                                                              acc[m][n], 0, 0, 0);
          acc[m][n] = __builtin_amdgcn_mfma_f32_16x16x32_bf16(ah[m], bl[n],
                                                              acc[m][n], 0, 0, 0);
          if (TERMS == 3)
            acc[m][n] = __builtin_amdgcn_mfma_f32_16x16x32_bf16(
                al[m], bh[n], acc[m][n], 0, 0, 0);
        }
    }
    __syncthreads();
  }
  const size_t cb = (size_t)z * cStride;
#pragma unroll
  for (int m = 0; m < 4; ++m) {
#pragma unroll
    for (int n = 0; n < 4; ++n) {
      const int c = n0 + wc * 64 + n * 16 + lr;
#pragma unroll
      for (int j = 0; j < 4; ++j) {
        const int r = m0 + wr * 64 + m * 16 + lg * 4 + j;
        float v = acc[m][n][j];
        if (EP == 1) v += bias[c] + addv[c] + addm[(size_t)r * N + c];
        if (EP == 2) v += bias[c];
        const size_t idx = cb + (size_t)r * N + c;
        if (EP == 1 || EP == 2) outF[idx] = v;
        if (EP == 0 || EP == 1) {
          const u16 h = f2b(v);
          outH[idx] = h;
          outL[idx] = f2b(v - b2f(h));
        }
      }
    }
  }
}

// -------- Flash attention, split-bf16 (hi/lo) MFMA, fp32-class accuracy ----
__global__ __launch_bounds__(256) void k_attn(const float* __restrict__ qkv,
                                              float* __restrict__ oatt) {
  const int q0 = blockIdx.x * 64, h = blockIdx.y, b = blockIdx.z;
  const int t = threadIdx.x;
  const int w = t >> 6, l = t & 63;
  const int lr = l & 15, lg = l >> 4;
  __shared__ u16 Ksh[64][64], Ksl[64][64];
  __shared__ u16 Vth[64][64], Vtl[64][64];
  __shared__ u16 Psh[64][64], Psl[64][64];  // doubles as Q staging
  const int sr_ = t >> 2;
  const int sc_ = (t & 3) * 16;
  {
    const float* src =
        qkv + (size_t)(b * NSEQ + q0 + sr_) * (3 * DMODEL) + h * HDIM;
#pragma unroll
    for (int i = 0; i < 4; ++i) {
      float4 v = *(const float4*)(src + sc_ + i * 4);
      v.x *= 0.125f; v.y *= 0.125f; v.z *= 0.125f; v.w *= 0.125f;
      ushort4 h4, l4;
      h4.x = f2b(v.x); l4.x = f2b(v.x - b2f(h4.x));
      h4.y = f2b(v.y); l4.y = f2b(v.y - b2f(h4.y));
      h4.z = f2b(v.z); l4.z = f2b(v.z - b2f(h4.z));
      h4.w = f2b(v.w); l4.w = f2b(v.w - b2f(h4.w));
      const int cs = (sc_ + i * 4) ^ ((sr_ & 7) << 3);
      *(ushort4*)&Psh[sr_][cs] = h4;
      *(ushort4*)&Psl[sr_][cs] = l4;
    }
  }
  __syncthreads();
  bf16x8_t qh[2], ql[2];
#pragma unroll
  for (int kc = 0; kc < 2; ++kc) {
    const int cs = (kc * 32 + lg * 8) ^ ((lr & 7) << 3);
    qh[kc] = *(const bf16x8_t*)&Psh[w * 16 + lr][cs];
    ql[kc] = *(const bf16x8_t*)&Psl[w * 16 + lr][cs];
  }
  float mrow[4] = {-1e30f, -1e30f, -1e30f, -1e30f};
  float lrow[4] = {0.f, 0.f, 0.f, 0.f};
  f32x4_t acc_o[4] = {};
  for (int k0 = 0; k0 < NSEQ; k0 += 64) {
    __syncthreads();
    {
      const float* kp =
          qkv + (size_t)(b * NSEQ + k0 + sr_) * (3 * DMODEL) + DMODEL + h * HDIM;
#pragma unroll
      for (int i = 0; i < 4; ++i) {
        float4 kv4 = *(const float4*)(kp + sc_ + i * 4);
        ushort4 h4, l4;
        h4.x = f2b(kv4.x); l4.x = f2b(kv4.x - b2f(h4.x));
        h4.y = f2b(kv4.y); l4.y = f2b(kv4.y - b2f(h4.y));
        h4.z = f2b(kv4.z); l4.z = f2b(kv4.z - b2f(h4.z));
        h4.w = f2b(kv4.w); l4.w = f2b(kv4.w - b2f(h4.w));
        const int cs = (sc_ + i * 4) ^ ((sr_ & 7) << 3);
        *(ushort4*)&Ksh[sr_][cs] = h4;
        *(ushort4*)&Ksl[sr_][cs] = l4;
      }
#pragma unroll
      for (int i = 0; i < 4; ++i) {
        const int d0 = (t & 3) * 4 + i * 16;
        const float4 vv4 = *(const float4*)(kp + DMODEL + d0);
#pragma unroll
        for (int jj = 0; jj < 4; ++jj) {
          const float f = (jj == 0) ? vv4.x : (jj == 1) ? vv4.y
                                   : (jj == 2) ? vv4.z : vv4.w;
          const u16 hi = f2b(f);
          const u16 lo = f2b(f - b2f(hi));
          const int d = d0 + jj;
          const int cs = sr_ ^ ((d & 7) << 3);
          Vth[d][cs] = hi;
          Vtl[d][cs] = lo;
        }
      }
    }
    __syncthreads();
    f32x4_t sacc[4] = {};
#pragma unroll
    for (int kc = 0; kc < 2; ++kc) {
#pragma unroll
      for (int n = 0; n < 4; ++n) {
        const int cs = (kc * 32 + lg * 8) ^ ((lr & 7) << 3);
        const bf16x8_t kh = *(const bf16x8_t*)&Ksh[n * 16 + lr][cs];
        const bf16x8_t kl = *(const bf16x8_t*)&Ksl[n * 16 + lr][cs];
        sacc[n] = __builtin_amdgcn_mfma_f32_16x16x32_bf16(qh[kc], kh, sacc[n], 0, 0, 0);
        sacc[n] = __builtin_amdgcn_mfma_f32_16x16x32_bf16(qh[kc], kl, sacc[n], 0, 0, 0);
        sacc[n] = __builtin_amdgcn_mfma_f32_16x16x32_bf16(ql[kc], kh, sacc[n], 0, 0, 0);
      }
    }
    float alpha[4];
#pragma unroll
    for (int j = 0; j < 4; ++j) {
      float mx = fmaxf(fmaxf(sacc[0][j], sacc[1][j]),
                       fmaxf(sacc[2][j], sacc[3][j]));
      mx = fmaxf(mx, __shfl_xor(mx, 1));
      mx = fmaxf(mx, __shfl_xor(mx, 2));
      mx = fmaxf(mx, __shfl_xor(mx, 4));
      mx = fmaxf(mx, __shfl_xor(mx, 8));
      const float mnew = fmaxf(mrow[j], mx);
      alpha[j] = __expf(mrow[j] - mnew);
      mrow[j] = mnew;
      float psum = 0.f;
      const int prow = lg * 4 + j;
#pragma unroll
      for (int n = 0; n < 4; ++n) {
        const float p = __expf(sacc[n][j] - mnew);
        psum += p;
        const u16 hi = f2b(p);
        const u16 lo = f2b(p - b2f(hi));
        const int pcol = (n * 16 + lr) ^ ((prow & 7) << 3);
        Psh[w * 16 + prow][pcol] = hi;
        Psl[w * 16 + prow][pcol] = lo;
      }
      psum += __shfl_xor(psum, 1);
      psum += __shfl_xor(psum, 2);
      psum += __shfl_xor(psum, 4);
      psum += __shfl_xor(psum, 8);
      lrow[j] = lrow[j] * alpha[j] + psum;
    }
#pragma unroll
    for (int n = 0; n < 4; ++n) {
#pragma unroll
      for (int j = 0; j < 4; ++j) acc_o[n][j] *= alpha[j];
    }
#pragma unroll
    for (int kc = 0; kc < 2; ++kc) {
      const int cs = (kc * 32 + lg * 8) ^ ((lr & 7) << 3);
      const bf16x8_t ph = *(const bf16x8_t*)&Psh[w * 16 + lr][cs];
      const bf16x8_t pl = *(const bf16x8_t*)&Psl[w * 16 + lr][cs];
#pragma unroll
      for (int n = 0; n < 4; ++n) {
        const bf16x8_t vh = *(const bf16x8_t*)&Vth[n * 16 + lr][cs];
        const bf16x8_t vl = *(const bf16x8_t*)&Vtl[n * 16 + lr][cs];
        acc_o[n] = __builtin_amdgcn_mfma_f32_16x16x32_bf16(ph, vh, acc_o[n], 0, 0, 0);
        acc_o[n] = __builtin_amdgcn_mfma_f32_16x16x32_bf16(ph, vl, acc_o[n], 0, 0, 0);
        acc_o[n] = __builtin_amdgcn_mfma_f32_16x16x32_bf16(pl, vh, acc_o[n], 0, 0, 0);
      }
    }
  }
#pragma unroll
  for (int j = 0; j < 4; ++j) {
    const float invl = 1.0f / lrow[j];
    float* dst =
        oatt + (size_t)(b * NSEQ + q0 + w * 16 + lg * 4 + j) * DMODEL + h * HDIM;
#pragma unroll
    for (int n = 0; n < 4; ++n) dst[n * 16 + lr] = acc_o[n][j] * invl;
  }
}

// ---------------- LayerNorm( a + b ) -> x2 (f32) + x2b (bf16) --------------
__global__ __launch_bounds__(256) void k_ln_add(
    const float* __restrict__ a, const float* __restrict__ bsrc,
    const float* __restrict__ g, const float* __restrict__ be,
    float* __restrict__ outp, u16* __restrict__ outb) {
  const int tok = blockIdx.x;
  const int t = threadIdx.x;
  float2 v;
  {
    const float2 va = *(const float2*)(a + (size_t)tok * DMODEL + t * 2);
    const float2 vb = *(const float2*)(bsrc + (size_t)tok * DMODEL + t * 2);
    v.x = va.x + vb.x; v.y = va.y + vb.y;
  }
  float s1 = v.x + v.y, s2 = v.x * v.x + v.y * v.y;
#pragma unroll
  for (int o = 32; o; o >>= 1) { s1 += __shfl_down(s1, o); s2 += __shfl_down(s2, o); }
  __shared__ float sm1[4], sm2[4];
  if ((t & 63) == 0) { sm1[t >> 6] = s1; sm2[t >> 6] = s2; }
  __syncthreads();
  s1 = sm1[0] + sm1[1] + sm1[2] + sm1[3];
  s2 = sm2[0] + sm2[1] + sm2[2] + sm2[3];
  const float mean = s1 * (1.f / DMODEL);
  const float var = s2 * (1.f / DMODEL) - mean * mean;
  const float rstd = rsqrtf(var + 1e-5f);
  float2 o;
  o.x = (v.x - mean) * rstd * g[t * 2] + be[t * 2];
  o.y = (v.y - mean) * rstd * g[t * 2 + 1] + be[t * 2 + 1];
  *(float2*)(outp + (size_t)tok * DMODEL + t * 2) = o;
  ushort2 ob;
  ob.x = f2b(o.x); ob.y = f2b(o.y);
  *(ushort2*)(outb + (size_t)tok * DMODEL + t * 2) = ob;
}

// ---------------- MoE gating (fp32 x2) -------------------------------------
__global__ __launch_bounds__(256) void k_gate(const float* __restrict__ x2,
                                              const float* __restrict__ gw,
                                              int* __restrict__ eidx,
                                              float* __restrict__ ewgt,
                                              int* __restrict__ ecnt) {
  const int tok = blockIdx.x * 256 + threadIdx.x;
  float lg[NEXP] = {};
  const float* px = x2 + (size_t)tok * DMODEL;
  for (int i = 0; i < DMODEL; i += 4) {
    const float4 xv = *(const float4*)(px + i);
#pragma unroll
    for (int e = 0; e < NEXP; ++e) {
      const float4 wv = *(const float4*)(gw + e * DMODEL + i);
      lg[e] += xv.x * wv.x + xv.y * wv.y + xv.z * wv.z + xv.w * wv.w;
    }
  }
  int i0 = 0; float b0 = lg[0];
#pragma unroll
  for (int e = 1; e < NEXP; ++e) if (lg[e] > b0) { b0 = lg[e]; i0 = e; }
  int i1 = -1; float v1 = -1e30f;
#pragma unroll
  for (int e = 0; e < NEXP; ++e)
    if (e != i0 && lg[e] > v1) { v1 = lg[e]; i1 = e; }
  const float tt = __expf(v1 - b0);
  const float w0 = 1.f / (1.f + tt), w1 = tt / (1.f + tt);
  eidx[tok * 2] = i0; eidx[tok * 2 + 1] = i1;
  ewgt[tok * 2] = w0; ewgt[tok * 2 + 1] = w1;
  atomicAdd(&ecnt[i0], 1);
  atomicAdd(&ecnt[i1], 1);
}

__global__ void k_zero(int* __restrict__ p, int n) {
  const int i = blockIdx.x * blockDim.x + threadIdx.x;
  if (i < n) p[i] = 0;
}

__global__ void k_offsets(const int* __restrict__ ecnt, int* __restrict__ eoff) {
  if (threadIdx.x == 0) {
    int s = 0;
    for (int e = 0; e < NEXP; ++e) { eoff[e] = s; s += ecnt[e]; }
  }
}

__global__ __launch_bounds__(256) void k_scatter(
    const int* __restrict__ eidx, const int* __restrict__ eoff,
    int* __restrict__ efill, int* __restrict__ rtok, int* __restrict__ t2s) {
  const int tok = blockIdx.x * 256 + threadIdx.x;
#pragma unroll
  for (int k = 0; k < 2; ++k) {
    const int e = eidx[tok * 2 + k];
    const int pos = atomicAdd(&efill[e], 1);
    const int slot = eoff[e] + pos;
    rtok[slot] = tok;
    t2s[tok * 2 + k] = slot;
  }
}

// ------------- transpose-convert f32 [R][C] -> bf16 [C][R], per expert -----
__global__ __launch_bounds__(256) void k_cvt_t(const float* __restrict__ src,
                                               u16* __restrict__ dst,
                                               int R, int C) {
  const int e = blockIdx.z;
  src += (size_t)e * R * C;
  dst += (size_t)e * R * C;
  const int r0 = blockIdx.y * 64, c0 = blockIdx.x * 64;
  __shared__ u16 tile[64][65];
  const int t = threadIdx.x;
  const int cc = t & 63, rb = t >> 6;
#pragma unroll
  for (int i = 0; i < 16; ++i) {
    const int r = i * 4 + rb;
    tile[r][cc] = f2b(src[(size_t)(r0 + r) * C + c0 + cc]);
  }
  __syncthreads();
#pragma unroll
  for (int i = 0; i < 16; ++i) {
    const int r = i * 4 + rb;
    dst[(size_t)(c0 + r) * R + r0 + cc] = tile[cc][r];
  }
}

// ------------- MoE MFMA GEMM, 128x128 tile, BK=64, 4 waves (2x2) -----------
template <int MODE>
__global__ __launch_bounds__(256) void k_moe_mfma(
    const u16* __restrict__ Ab, const u16* __restrict__ Bb,
    const float* __restrict__ bias, const int* __restrict__ rtok,
    const int* __restrict__ ecnt, const int* __restrict__ eoff,
    u16* __restrict__ outp) {
  constexpr int K = (MODE == 0) ? DMODEL : DF;
  constexpr int N = (MODE == 0) ? DF : DMODEL;
  const int e = blockIdx.z;
  const int cnt = ecnt[e];
  const int m0 = blockIdx.y * 128;
  if (m0 >= cnt) return;
  const int off = eoff[e];
  const int n0 = blockIdx.x * 128;
  const u16* Bw = Bb + (size_t)e * (size_t)K * N;  // [N][K] bf16
  __shared__ u16 As[128][64];
  __shared__ u16 Bs[128][64];
  const int t = threadIdx.x;
  const int w = t >> 6, l = t & 63;
  const int srow = w * 8 + (l >> 3);
  const int scol = (l & 7) * 8;
  const u16* arow[4];
#pragma unroll
  for (int i = 0; i < 4; ++i) {
    const int r = m0 + i * 32 + srow;
    const int rr = (r < cnt) ? r : (cnt - 1);
    if (MODE == 0)
      arow[i] = Ab + (size_t)rtok[off + rr] * K + scol;
    else
      arow[i] = Ab + ((size_t)off + rr) * K + scol;
  }
  const u16* brow[4];
#pragma unroll
  for (int i = 0; i < 4; ++i)
    brow[i] = Bw + (size_t)(n0 + i * 32 + srow) * K + scol;

  const int wr = w >> 1, wc = w & 1;
  const int lr = l & 15, lg = l >> 4;
  f32x4_t acc[4][4] = {};
  for (int k0 = 0; k0 < K; k0 += 64) {
#pragma unroll
    for (int i = 0; i < 4; ++i) {
      gl_lds16(arow[i] + k0, &As[i * 32 + w * 8][0]);
      gl_lds16(brow[i] + k0, &Bs[i * 32 + w * 8][0]);
    }
    __syncthreads();
#pragma unroll
    for (int kk = 0; kk < 2; ++kk) {
      bf16x8_t af[4], bfr[4];
#pragma unroll
      for (int m = 0; m < 4; ++m)
        af[m] = *(const bf16x8_t*)&As[wr * 64 + m * 16 + lr][kk * 32 + lg * 8];
#pragma unroll
      for (int n = 0; n < 4; ++n)
        bfr[n] = *(const bf16x8_t*)&Bs[wc * 64 + n * 16 + lr][kk * 32 + lg * 8];
#pragma unroll
      for (int m = 0; m < 4; ++m)
#pragma unroll
        for (int n = 0; n < 4; ++n)
          acc[m][n] = __builtin_amdgcn_mfma_f32_16x16x32_bf16(
              af[m], bfr[n], acc[m][n], 0, 0, 0);
    }
    __syncthreads();
  }
#pragma unroll
  for (int m = 0; m < 4; ++m) {
    const int rl0 = wr * 64 + m * 16 + lg * 4;
#pragma unroll
    for (int n = 0; n < 4; ++n) {
      const int gc = n0 + wc * 64 + n * 16 + lr;
      const float bv = bias[e * N + gc];
#pragma unroll
      for (int j = 0; j < 4; ++j) {
        const int r = m0 + rl0 + j;
        if (r < cnt) {
          float v = acc[m][n][j] + bv;
          if (MODE == 0) v = v * 0.5f * (1.f + erff(v * 0.70710678118f));
          outp[((size_t)off + r) * N + gc] = f2b(v);
        }
      }
    }
  }
}

// -------- combine: out = LN( x2 + w0*y[s0] + w1*y[s1] ), y in bf16 ---------
__global__ __launch_bounds__(256) void k_ln2(
    const float* __restrict__ x2, const u16* __restrict__ ybuf,
    const int* __restrict__ t2s, const float* __restrict__ ewgt,
    const float* __restrict__ g, const float* __restrict__ be,
    float* __restrict__ outp) {
  const int tok = blockIdx.x;
  const int t = threadIdx.x;
  const int s0 = t2s[tok * 2], s1i = t2s[tok * 2 + 1];
  const float w0 = ewgt[tok * 2], w1 = ewgt[tok * 2 + 1];
  float2 v;
  {
    const float2 a = *(const float2*)(x2 + (size_t)tok * DMODEL + t * 2);
    const ushort2 y0 = *(const ushort2*)(ybuf + (size_t)s0 * DMODEL + t * 2);
    const ushort2 y1 = *(const ushort2*)(ybuf + (size_t)s1i * DMODEL + t * 2);
    v.x = a.x + w0 * b2f(y0.x) + w1 * b2f(y1.x);
    v.y = a.y + w0 * b2f(y0.y) + w1 * b2f(y1.y);
  }
  float sum1 = v.x + v.y, sum2 = v.x * v.x + v.y * v.y;
#pragma unroll
  for (int o = 32; o; o >>= 1) { sum1 += __shfl_down(sum1, o); sum2 += __shfl_down(sum2, o); }
  __shared__ float sm1[4], sm2[4];
  if ((t & 63) == 0) { sm1[t >> 6] = sum1; sm2[t >> 6] = sum2; }
  __syncthreads();
  sum1 = sm1[0] + sm1[1] + sm1[2] + sm1[3];
  sum2 = sm2[0] + sm2[1] + sm2[2] + sm2[3];
  const float mean = sum1 * (1.f / DMODEL);
  const float var = sum2 * (1.f / DMODEL) - mean * mean;
  const float rstd = rsqrtf(var + 1e-5f);
  float2 o;
  o.x = (v.x - mean) * rstd * g[t * 2] + be[t * 2];
  o.y = (v.y - mean) * rstd * g[t * 2 + 1] + be[t * 2 + 1];
  *(float2*)(outp + (size_t)tok * DMODEL + t * 2) = o;
}

extern "C" void kernel_launch(void* const* d_in, const int* in_sizes, int n_in,
                              void* d_out, int out_size, void* d_ws,
                              size_t ws_size, hipStream_t stream) {
  const float* x      = (const float*)d_in[0];
  const float* adj    = (const float*)d_in[1];
  const float* gc_w   = (const float*)d_in[2];
  const float* gc_b   = (const float*)d_in[3];
  const float* root   = (const float*)d_in[4];
  const float* in_w   = (const float*)d_in[5];
  const float* in_b   = (const float*)d_in[6];
  const float* out_w  = (const float*)d_in[7];
  const float* out_b  = (const float*)d_in[8];
  const float* ln1_g  = (const float*)d_in[9];
  const float* ln1_b  = (const float*)d_in[10];
  const float* ln2_g  = (const float*)d_in[11];
  const float* ln2_b  = (const float*)d_in[12];
  const float* gate_w = (const float*)d_in[13];
  const float* W1     = (const float*)d_in[14];
  const float* b1     = (const float*)d_in[15];
  const float* W2     = (const float*)d_in[16];
  const float* b2     = (const float*)d_in[17];
  float* outp = (float*)d_out;

  // ws layout (peak 112.3 MB, same footprint as proven rounds). Lifetimes:
  //  [0,16)  adj_bf -> qkv head -> oatth/oattl -> ybuf
  //  [16,32) xht/xlt -> qkv -> oproj -> hid head
  //  [32,48) axh/axl -> qkv -> hid
  //  [48,64) x1 f32 (gc -> LN1); then hid
  //  [64,80) x1h/x1l (gc -> qkv); then hid
  //  [80,96) oatt (attn -> cvt); then Wxb (W1b/W2b)
  //  [96,112) x2 f32
  //  [112,..) misc routing
  //  d_out scratch: weight splits [0,5MB) (dead by LN1) -> x2b [0,8MB)
  constexpr size_t MB = 1ull << 20;
  char* W = (char*)d_ws;
  u16*   adj_bf = (u16*)(W + 0);
  u16*   xht    = (u16*)(W + 16 * MB);
  u16*   xlt    = (u16*)(W + 24 * MB);
  u16*   axh    = (u16*)(W + 32 * MB);
  u16*   axl    = (u16*)(W + 40 * MB);
  float* qkv    = (float*)(W + 0);
  float* x1     = (float*)(W + 48 * MB);
  u16*   x1h    = (u16*)(W + 64 * MB);
  u16*   x1l    = (u16*)(W + 72 * MB);
  float* oatt   = (float*)(W + 80 * MB);
  u16*   oatth  = (u16*)(W + 0);
  u16*   oattl  = (u16*)(W + 8 * MB);
  float* oproj  = (float*)(W + 16 * MB);
  float* x2     = (float*)(W + 96 * MB);
  u16*   Wxb    = (u16*)(W + 80 * MB);
  u16*   hid    = (u16*)(W + 16 * MB);
  u16*   ybuf   = (u16*)(W + 0);
  char*  misc   = W + 112 * MB;
  char*  Od     = (char*)d_out;
  u16*   gwh = (u16*)(Od + 0);
  u16*   gwl = (u16*)(Od + 512 * 1024);
  u16*   iwh = (u16*)(Od + 1 * MB);
  u16*   iwl = (u16*)(Od + 1 * MB + 1536 * 1024);
  u16*   owh = (u16*)(Od + 4 * MB);
  u16*   owl = (u16*)(Od + 4 * MB + 512 * 1024);
  u16*   x2b = (u16*)d_out;
  int*   eidx  = (int*)misc;
  float* ewgt  = (float*)(misc + 65536);
  int*   ecnt  = (int*)(misc + 131072);
  int*   eoff  = (int*)(misc + 131072 + 128);
  int*   efill = (int*)(misc + 131072 + 256);
  int*   rtok  = (int*)(misc + 131072 + 512);
  int*   t2s   = (int*)(misc + 131072 + 512 + 65536);

  // conversions: adj (exact bf16), x^T hi/lo, weight splits
  k_cvt_b<<<dim3(8192), 256, 0, stream>>>(adj, adj_bf, NB * NSEQ * NSEQ / 4);
  k_cvt_t_hl<<<dim3(8, 16, 8), 256, 0, stream>>>(x, xht, xlt, NSEQ, DMODEL);
  k_cvt_hl<<<dim3(256), 256, 0, stream>>>(gc_w, gwh, gwl, DMODEL * DMODEL / 4);
  k_cvt_hl<<<dim3(768), 256, 0, stream>>>(in_w, iwh, iwl, 3 * DMODEL * DMODEL / 4);
  k_cvt_hl<<<dim3(256), 256, 0, stream>>>(out_w, owh, owl, DMODEL * DMODEL / 4);
  // A: ax = adj @ x  (2-term split MFMA, per batch) -> axh/axl
  k_gemm_sp<2, 0><<<dim3(4, 8, 8), 256, 0, stream>>>(
      adj_bf, nullptr, xht, xlt, nullptr, nullptr, nullptr, nullptr, axh, axl,
      NSEQ, DMODEL, (size_t)NSEQ * NSEQ, (size_t)DMODEL * NSEQ,
      (size_t)NSEQ * DMODEL);
  // B: x1 = x + ax @ gc_w^T + gc_b + root  -> x1 f32 + x1h/x1l
  k_gemm_sp<3, 1><<<dim3(4, 64, 1), 256, 0, stream>>>(
      axh, axl, gwh, gwl, gc_b, root, x, x1, x1h, x1l, DMODEL, DMODEL, 0, 0, 0);
  // C: qkv = x1 @ in_w^T + in_b  (f32 out)
  k_gemm_sp<3, 2><<<dim3(12, 64, 1), 256, 0, stream>>>(
      x1h, x1l, iwh, iwl, in_b, nullptr, nullptr, qkv, nullptr, nullptr,
      DMODEL, 3 * DMODEL, 0, 0, 0);
  // D: attention (split-bf16 MFMA)
  k_attn<<<dim3(16, 8, 8), 256, 0, stream>>>(qkv, oatt);
  // oatt -> hi/lo (qkv region dead)
  k_cvt_hl<<<dim3(4096), 256, 0, stream>>>(oatt, oatth, oattl,
                                           T_TOK * DMODEL / 4);
  // E: oproj = oatt @ out_w^T + out_b
  k_gemm_sp<3, 2><<<dim3(4, 64, 1), 256, 0, stream>>>(
      oatth, oattl, owh, owl, out_b, nullptr, nullptr, oproj, nullptr, nullptr,
      DMODEL, DMODEL, 0, 0, 0);
  // LN1: x2 (f32) + x2b (bf16, d_out scratch; weight splits dead now)
  k_ln_add<<<dim3(T_TOK), 256, 0, stream>>>(x1, oproj, ln1_g, ln1_b, x2, x2b);
  // MoE routing (fp32 gate)
  k_zero<<<dim3(1), 128, 0, stream>>>((int*)(misc + 131072), 128);
  k_gate<<<dim3(T_TOK / 256), 256, 0, stream>>>(x2, gate_w, eidx, ewgt, ecnt);
  k_offsets<<<dim3(1), 64, 0, stream>>>(ecnt, eoff);
  k_scatter<<<dim3(T_TOK / 256), 256, 0, stream>>>(eidx, eoff, efill, rtok, t2s);
  // MoE expert FFN (MFMA bf16); W1b into [80,96) (oatt dead)
  k_cvt_t<<<dim3(DF / 64, DMODEL / 64, NEXP), 256, 0, stream>>>(W1, Wxb,
                                                                DMODEL, DF);
  k_moe_mfma<0><<<dim3(DF / 128, 128, NEXP), 256, 0, stream>>>(
      x2b, Wxb, b1, rtok, ecnt, eoff, hid);
  k_cvt_t<<<dim3(DMODEL / 64, DF / 64, NEXP), 256, 0, stream>>>(W2, Wxb, DF,
                                                                DMODEL);
  k_moe_mfma<1><<<dim3(DMODEL / 128, 128, NEXP), 256, 0, stream>>>(
      hid, Wxb, b2, rtok, ecnt, eoff, ybuf);
  // combine + LN2 -> out
  k_ln2<<<dim3(T_TOK), 256, 0, stream>>>(x2, ybuf, t2s, ewgt, ln2_g, ln2_b,
                                         outp);
}